// Round 14
// baseline (887.394 us; speedup 1.0000x reference)
//
#include <hip/hip_runtime.h>
#include <hip/hip_bf16.h>
#include <cstdint>
#include <cstddef>

namespace {

constexpr int Hh = 512;
constexpr int G3 = 1536;   // 3*H
constexpr int Bb = 32;
constexpr int Tt = 64;
constexpr int Vv = 32000;

typedef __attribute__((ext_vector_type(8))) short short8;
typedef __attribute__((ext_vector_type(4))) float f32x4;
typedef unsigned long long ull;

__device__ __forceinline__ unsigned bf16bits(float f) {
  union { __hip_bfloat16 h; unsigned short u; } c;
  c.h = __float2bfloat16(f);
  return (unsigned)c.u;
}

// async global->LDS, 16B per lane; LDS dest = wave-uniform base + lane*16
__device__ __forceinline__ void gl_lds16(const void* g, void* l) {
  __builtin_amdgcn_global_load_lds(
      (const __attribute__((address_space(1))) unsigned int*)g,
      (__attribute__((address_space(3))) unsigned int*)l, 16, 0, 0);
}

// ---------------- merged preprocessing: cvt x2 | pack x2 | zero hTag_e+hTag_d+doneCnt ----------------
__device__ __forceinline__ void cvt_range(const float* __restrict__ src,
                                          __hip_bfloat16* __restrict__ dst, int i, int n4) {
  if (i >= n4) return;
  float4 v = ((const float4*)src)[i];
  union { __hip_bfloat16 h[4]; uint2 u; } o;
  o.h[0] = __float2bfloat16(v.x);
  o.h[1] = __float2bfloat16(v.y);
  o.h[2] = __float2bfloat16(v.z);
  o.h[3] = __float2bfloat16(v.w);
  ((uint2*)dst)[i] = o.u;
}

__device__ __forceinline__ void pack_whh_core(const float* __restrict__ Whh,
                                              uint2* __restrict__ P, int k0, int i0) {
  __shared__ float tw[3][32][65];
  const int t = threadIdx.x;               // 256
  const int kk = t & 63, r4 = t >> 6;
  for (int ri = r4; ri < 96; ri += 4) {
    const int g = ri >> 5, ii = ri & 31;
    tw[g][ii][kk] = Whh[(size_t)(g * 512 + i0 + ii) * 512 + k0 + kk];
  }
  __syncthreads();
  const int ii = t & 31, kq = t >> 5;
  for (int k2 = kq; k2 < 64; k2 += 8) {
    unsigned rb = bf16bits(tw[0][ii][k2]);
    unsigned zb = bf16bits(tw[1][ii][k2]);
    unsigned nb = bf16bits(tw[2][ii][k2]);
    P[(size_t)(k0 + k2) * 512 + i0 + ii] = make_uint2((zb << 16) | rb, nb);
  }
}

__global__ __launch_bounds__(256) void prep_k(
    const float* __restrict__ enc_Wih, __hip_bfloat16* __restrict__ encWih_bf,
    const float* __restrict__ dec_Wih, __hip_bfloat16* __restrict__ decWih_bf,
    const float* __restrict__ enc_Whh, uint2* __restrict__ whhB_e,
    const float* __restrict__ dec_Whh, uint2* __restrict__ whhB_d,
    uint4* __restrict__ zeroBase) {
  const int blk = blockIdx.x;
  if (blk < 768) {
    cvt_range(enc_Wih, encWih_bf, blk * 256 + threadIdx.x, 1536 * 512 / 4);
  } else if (blk < 2304) {
    cvt_range(dec_Wih, decWih_bf, (blk - 768) * 256 + threadIdx.x, 1536 * 1024 / 4);
  } else if (blk < 2432) {
    const int b = blk - 2304;
    pack_whh_core(enc_Whh, whhB_e, (b & 7) * 64, (b >> 3) * 32);
  } else if (blk < 2560) {
    const int b = blk - 2432;
    pack_whh_core(dec_Whh, whhB_d, (b & 7) * 64, (b >> 3) * 32);
  } else {
    // zero hTag_e + hTag_d + doneCnt (contiguous): 131136 u32 = 32784 uint4
    const int i = (blk - 2560) * 256 + threadIdx.x;
    if (i < 32784) zeroBase[i] = make_uint4(0u, 0u, 0u, 0u);
  }
}

// ---------------- embedding gather (optionally relu) -> bf16 [2048][512] ----------------
__global__ void embed_k(const int* __restrict__ idx, const float* __restrict__ emb,
                        __hip_bfloat16* __restrict__ outp, int do_relu) {
  int row = blockIdx.x;            // 0..2047 (= b*64+t)
  int r = idx[row];
  float4 v = ((const float4*)(emb + (size_t)r * Hh))[threadIdx.x];  // 128 thr * 4
  if (do_relu) {
    v.x = fmaxf(v.x, 0.f); v.y = fmaxf(v.y, 0.f);
    v.z = fmaxf(v.z, 0.f); v.w = fmaxf(v.w, 0.f);
  }
  union { __hip_bfloat16 h[4]; uint2 u; } o;
  o.h[0] = __float2bfloat16(v.x);
  o.h[1] = __float2bfloat16(v.y);
  o.h[2] = __float2bfloat16(v.z);
  o.h[3] = __float2bfloat16(v.w);
  ((uint2*)(outp + (size_t)row * Hh))[threadIdx.x] = o.u;
}

// ---------------- bf16 MFMA GEMM (standalone, f32 out + bias): used for enc_xp only ----------------
__global__ __launch_bounds__(256) void gemm_bf16_k(
    const __hip_bfloat16* __restrict__ A,
    const __hip_bfloat16* __restrict__ B,
    float* __restrict__ C,
    int lda, int ldb, int ldc, int K,
    const float* __restrict__ bias1,
    int ntm) {
  __shared__ __align__(16) char smem[32768];
  auto sA = (__hip_bfloat16(*)[64])smem;            // [128][64]
  auto sB = (__hip_bfloat16(*)[64])(smem + 16384);  // [128][64]

  const unsigned nwg = gridDim.x, gid = blockIdx.x;
  const unsigned q = nwg >> 3, r8 = nwg & 7, xc = gid & 7, jj = gid >> 3;
  const unsigned wg = (xc < r8 ? xc * (q + 1) : r8 * (q + 1) + (xc - r8) * q) + jj;
  const int m0 = (int)(wg % (unsigned)ntm) << 7;
  const int n0 = (int)(wg / (unsigned)ntm) << 7;

  const int tid = threadIdx.x;
  const int l = tid & 63, w = tid >> 6;
  const int wm = (w & 1) << 6, wn = (w >> 1) << 6;
  const int lr = l & 15;
  const int lk = (l >> 4) << 3;
  const int lrow = (w << 3) + (l >> 3);
  const int lcol = (l & 7) << 3;

  f32x4 acc[4][4];
  #pragma unroll
  for (int i = 0; i < 4; ++i)
    #pragma unroll
    for (int j = 0; j < 4; ++j) acc[i][j] = {0.f, 0.f, 0.f, 0.f};

  for (int k0 = 0; k0 < K; k0 += 64) {
    #pragma unroll
    for (int rr = 0; rr < 4; ++rr) {
      gl_lds16(A + (size_t)(m0 + (rr << 5) + lrow) * lda + k0 + lcol, &sA[(rr << 5) + (w << 3)][0]);
      gl_lds16(B + (size_t)(n0 + (rr << 5) + lrow) * ldb + k0 + lcol, &sB[(rr << 5) + (w << 3)][0]);
    }
    __syncthreads();
    #pragma unroll
    for (int kk = 0; kk < 64; kk += 32) {
      short8 aF[4], bF[4];
      #pragma unroll
      for (int ms = 0; ms < 4; ++ms) aF[ms] = *(const short8*)(&sA[wm + (ms << 4) + lr][kk + lk]);
      #pragma unroll
      for (int ns = 0; ns < 4; ++ns) bF[ns] = *(const short8*)(&sB[wn + (ns << 4) + lr][kk + lk]);
      #pragma unroll
      for (int ms = 0; ms < 4; ++ms)
        #pragma unroll
        for (int ns = 0; ns < 4; ++ns)
          acc[ms][ns] = __builtin_amdgcn_mfma_f32_16x16x32_bf16(aF[ms], bF[ns], acc[ms][ns], 0, 0, 0);
    }
    __syncthreads();
  }

  float* sg = (float*)smem + w * 1088;
  const int r2w = l >> 4;
  const int cw = l & 15;
  const int rbase = r2w << 2;
  #pragma unroll
  for (int ms = 0; ms < 4; ++ms) {
    #pragma unroll
    for (int ns = 0; ns < 4; ++ns)
      #pragma unroll
      for (int r = 0; r < 4; ++r) sg[(rbase + r) * 68 + (ns << 4) + lr] = acc[ms][ns][r];
    #pragma unroll
    for (int qq = 0; qq < 4; ++qq) {
      const int srow2 = (qq << 2) + r2w;
      float4 v = *(const float4*)&sg[srow2 * 68 + (cw << 2)];
      const int row = m0 + wm + (ms << 4) + srow2;
      const int col = n0 + wn + (cw << 2);
      if (bias1) {
        float4 b1 = *(const float4*)&bias1[col];
        v.x += b1.x; v.y += b1.y; v.z += b1.z; v.w += b1.w;
      }
      *(float4*)&C[(size_t)row * ldc + col] = v;
    }
  }
}

// ---------------- GRU core (v5 protocol, proven) + reg-hoisted bhh/tp; [t][b] UC dec_out + doneCnt ----------------
__device__ __forceinline__ void gru_core(
    const int slice, const int bg,
    const float* __restrict__ xp, const uint2* __restrict__ whhB,
    const float* __restrict__ bhh,
    ull* __restrict__ hTag, unsigned* __restrict__ decOutU,  // null or u32-packed bf16 [2048*512/2], row r2=t*32+bb
    unsigned* __restrict__ doneCnt,                          // null or [64]
    char* smem,
    const ull* __restrict__ thoughtTag,   // null or encoder hTag buf0 (thought w/ tag 64)
    const float* __restrict__ decWih,     // f32 [1536][1024] (only if thoughtTag)
    const float* __restrict__ dec_bih) {  // f32 [1536]       (only if thoughtTag)
  float* sH = (float*)smem;                 // 2048 f32 (8KB)
  float* sRed = (float*)(smem + 8192);      // 512*13 f32 (26.6KB)
  const int tid = threadIdx.x;
  const int i0 = slice << 5;
  const int il = tid & 31, kc = tid >> 5;   // 32 i x 16 k-chunks(32k each)
  const int kb0 = kc << 5;

  // ---- step-invariant weights -> 96 VGPRs ----
  float wrF[32], wzF[32], wnF[32];
  {
    const uint2* wp = whhB + i0 + il;
    #pragma unroll
    for (int k4 = 0; k4 < 8; ++k4) {
      #pragma unroll
      for (int j = 0; j < 4; ++j) {
        const int idx = (k4 << 2) + j;
        uint2 wv = wp[(size_t)(kb0 + idx) << 9];
        wrF[idx] = __uint_as_float(wv.x << 16);
        wzF[idx] = __uint_as_float(wv.x & 0xffff0000u);
        wnF[idx] = __uint_as_float(wv.y << 16);
      }
    }
  }

  // ---- tail invariants: bhh, tp (thought projection) ----
  float bh_r = 0.f, bh_z = 0.f, bh_n = 0.f;
  float tpr = 0.f, tpz = 0.f, tpn = 0.f;
  int gi = 0, bb = 0;
  if (tid < 128) {
    const int b = tid >> 5, i2 = tid & 31;
    gi = i0 + i2;
    bb = (bg << 2) + b;
    bh_r = bhh[gi]; bh_z = bhh[512 + gi]; bh_n = bhh[1024 + gi];
  }
  if (thoughtTag) {
    #pragma unroll
    for (int j = 0; j < 4; ++j) {
      ull v = __hip_atomic_load(thoughtTag + ((size_t)bg << 11) + (j << 9) + tid,
                                __ATOMIC_RELAXED, __HIP_MEMORY_SCOPE_AGENT);
      sH[(j << 9) + tid] = fmaxf(__uint_as_float((unsigned)v), 0.f);
    }
    __syncthreads();
    if (tid < 384) {
      const int b = tid / 96, j = tid % 96;
      const int g = j >> 5, i2 = j & 31;
      const int row = g * 512 + i0 + i2;
      const float4* w4 = (const float4*)(decWih + (size_t)row * 1024 + 512);
      const float* th = &sH[b << 9];
      float s = dec_bih[row];
      #pragma unroll 4
      for (int k = 0; k < 128; ++k) {
        float4 w = w4[k];
        float4 t4 = *(const float4*)&th[k << 2];
        s += w.x * t4.x + w.y * t4.y + w.z * t4.z + w.w * t4.w;
      }
      sRed[tid] = s;
    }
    __syncthreads();
    if (tid < 128) {
      const int b = tid >> 5, i2 = tid & 31;
      tpr = sRed[b * 96 + i2];
      tpz = sRed[b * 96 + 32 + i2];
      tpn = sRed[b * 96 + 64 + i2];
    }
    __syncthreads();
  }

  #pragma unroll 1
  for (int t = 0; t < Tt; ++t) {
    // poll + load h(t) (tag word = {step<<32 | f32}, buffer = t parity)
    {
      const ull* hb = hTag + ((size_t)(t & 1) << 14) + ((size_t)bg << 11);
      #pragma unroll
      for (int j = 0; j < 4; ++j) {
        const ull* p = hb + (j << 9) + tid;
        ull v = __hip_atomic_load(p, __ATOMIC_RELAXED, __HIP_MEMORY_SCOPE_AGENT);
        while ((unsigned)(v >> 32) != (unsigned)t) {
          __builtin_amdgcn_s_sleep(1);
          v = __hip_atomic_load(p, __ATOMIC_RELAXED, __HIP_MEMORY_SCOPE_AGENT);
        }
        sH[(j << 9) + tid] = __uint_as_float((unsigned)v);
      }
    }
    __syncthreads();   // B0

    float a[12];
    #pragma unroll
    for (int v = 0; v < 12; ++v) a[v] = 0.f;
    #pragma unroll
    for (int k4 = 0; k4 < 8; ++k4) {
      const int kb = kb0 + (k4 << 2);
      float4 hv0 = *(const float4*)&sH[kb];
      float4 hv1 = *(const float4*)&sH[512 + kb];
      float4 hv2 = *(const float4*)&sH[1024 + kb];
      float4 hv3 = *(const float4*)&sH[1536 + kb];
      const float* h0p = (const float*)&hv0;
      const float* h1p = (const float*)&hv1;
      const float* h2p = (const float*)&hv2;
      const float* h3p = (const float*)&hv3;
      #pragma unroll
      for (int j = 0; j < 4; ++j) {
        const int idx = (k4 << 2) + j;
        const float wr = wrF[idx], wz = wzF[idx], wn = wnF[idx];
        a[0]  = fmaf(wr, h0p[j], a[0]);  a[1]  = fmaf(wz, h0p[j], a[1]);  a[2]  = fmaf(wn, h0p[j], a[2]);
        a[3]  = fmaf(wr, h1p[j], a[3]);  a[4]  = fmaf(wz, h1p[j], a[4]);  a[5]  = fmaf(wn, h1p[j], a[5]);
        a[6]  = fmaf(wr, h2p[j], a[6]);  a[7]  = fmaf(wz, h2p[j], a[7]);  a[8]  = fmaf(wn, h2p[j], a[8]);
        a[9]  = fmaf(wr, h3p[j], a[9]);  a[10] = fmaf(wz, h3p[j], a[10]); a[11] = fmaf(wn, h3p[j], a[11]);
      }
    }
    {
      float* red = &sRed[tid * 13];
      #pragma unroll
      for (int v = 0; v < 12; ++v) red[v] = a[v];
    }
    __syncthreads();   // B1

    if (tid < 128) {
      const int b = tid >> 5, i2 = tid & 31;
      float s0 = 0.f, s1 = 0.f, s2 = 0.f;
      #pragma unroll
      for (int kc2 = 0; kc2 < 16; ++kc2) {
        const float* rp = &sRed[(kc2 * 32 + i2) * 13 + b * 3];
        s0 += rp[0]; s1 += rp[1]; s2 += rp[2];
      }
      const float hr = s0 + bh_r;
      const float hz = s1 + bh_z;
      const float hn = s2 + bh_n;
      const size_t m = (size_t)bb * Tt + t;
      const float xr = xp[m * G3 + gi] + tpr;
      const float xz = xp[m * G3 + 512 + gi] + tpz;
      const float xn = xp[m * G3 + 1024 + gi] + tpn;
      const float rg = 1.f / (1.f + __expf(-(xr + hr)));
      const float zg = 1.f / (1.f + __expf(-(xz + hz)));
      const float ng = tanhf(xn + rg * hn);
      const float hnew = (1.f - zg) * ng + zg * sH[(b << 9) + gi];
      ull* dst = hTag + ((size_t)((t + 1) & 1) << 14) + ((size_t)bb << 9) + gi;
      __hip_atomic_store(dst, ((ull)(unsigned)(t + 1) << 32) | (ull)__float_as_uint(hnew),
                         __ATOMIC_RELAXED, __HIP_MEMORY_SCOPE_AGENT);
      if (decOutU) {
        // [t][b] layout, UC paired-u32 store: row r2=t*32+bb, col gi; even lane packs (gi, gi+1)
        unsigned bbits = bf16bits(hnew);
        unsigned pbits = __shfl_down(bbits, 1);
        if (!(tid & 1)) {
          const int r2 = (t << 5) + bb;
          __hip_atomic_store(decOutU + (((r2 << 9) + gi) >> 1), (pbits << 16) | bbits,
                             __ATOMIC_RELAXED, __HIP_MEMORY_SCOPE_AGENT);
        }
      }
    }
    __syncthreads();   // B2: drains UC stores (vmcnt 0) before flag
    if (doneCnt && tid == 0) {
      __hip_atomic_fetch_add(doneCnt + t, 1u, __ATOMIC_RELAXED, __HIP_MEMORY_SCOPE_AGENT);
    }
  }
}

// ---------------- 128x128 tile GEMM core (cached A+B, f32 out) for enc_fused dec_xp ----------------
__device__ __forceinline__ void gemm_tile_core(
    const int tid, const int m0, const int n0,
    const __hip_bfloat16* __restrict__ A, const __hip_bfloat16* __restrict__ B,
    float* __restrict__ C, int lda, int ldb, int ldc, int K, char* smem) {
  auto sA = (__hip_bfloat16(*)[64])smem;
  auto sB = (__hip_bfloat16(*)[64])(smem + 16384);
  const int l = tid & 63, w = tid >> 6;
  const int wm = (w & 1) << 6, wn = (w >> 1) << 6;
  const int lr = l & 15;
  const int lk = (l >> 4) << 3;
  const int lrow = (w << 3) + (l >> 3);
  const int lcol = (l & 7) << 3;

  f32x4 acc[4][4];
  #pragma unroll
  for (int i = 0; i < 4; ++i)
    #pragma unroll
    for (int j = 0; j < 4; ++j) acc[i][j] = {0.f, 0.f, 0.f, 0.f};

  for (int k0 = 0; k0 < K; k0 += 64) {
    #pragma unroll
    for (int rr = 0; rr < 4; ++rr) {
      gl_lds16(A + (size_t)(m0 + (rr << 5) + lrow) * lda + k0 + lcol, &sA[(rr << 5) + (w << 3)][0]);
      gl_lds16(B + (size_t)(n0 + (rr << 5) + lrow) * ldb + k0 + lcol, &sB[(rr << 5) + (w << 3)][0]);
    }
    __syncthreads();
    #pragma unroll
    for (int kk = 0; kk < 64; kk += 32) {
      short8 aF[4], bF[4];
      #pragma unroll
      for (int ms = 0; ms < 4; ++ms) aF[ms] = *(const short8*)(&sA[wm + (ms << 4) + lr][kk + lk]);
      #pragma unroll
      for (int ns = 0; ns < 4; ++ns) bF[ns] = *(const short8*)(&sB[wn + (ns << 4) + lr][kk + lk]);
      #pragma unroll
      for (int ms = 0; ms < 4; ++ms)
        #pragma unroll
        for (int ns = 0; ns < 4; ++ns)
          acc[ms][ns] = __builtin_amdgcn_mfma_f32_16x16x32_bf16(aF[ms], bF[ns], acc[ms][ns], 0, 0, 0);
    }
    __syncthreads();
  }

  float* sg = (float*)smem + w * 1088;
  const int r2w = l >> 4;
  const int cw = l & 15;
  const int rbase = r2w << 2;
  #pragma unroll
  for (int ms = 0; ms < 4; ++ms) {
    #pragma unroll
    for (int ns = 0; ns < 4; ++ns)
      #pragma unroll
      for (int r = 0; r < 4; ++r) sg[(rbase + r) * 68 + (ns << 4) + lr] = acc[ms][ns][r];
    #pragma unroll
    for (int qq = 0; qq < 4; ++qq) {
      const int srow2 = (qq << 2) + r2w;
      float4 v = *(const float4*)&sg[srow2 * 68 + (cw << 2)];
      *(float4*)&C[(size_t)(m0 + wm + (ms << 4) + srow2) * ldc + n0 + wn + (cw << 2)] = v;
    }
  }
}

// ---------------- logits tile core: A via UC 8B loads (coherence-safe in-kernel), B cached ----------------
// Output rows remapped r2->m=(bb<<6)+t in epilogue; emits partials + bf16/f32 logits.
__device__ __forceinline__ void gemm_logits_core(
    const int tid, const int m0, const int n0,
    const ull* __restrict__ Au,            // decOut packed, [t][b] rows, 512 cols bf16
    const __hip_bfloat16* __restrict__ B,  // outW_bf [32000][512]
    const float* __restrict__ out_b,
    float* __restrict__ outF, __hip_bfloat16* __restrict__ outBf,
    float2* __restrict__ partials, const int bfOut, char* smem) {
  auto sA = (__hip_bfloat16(*)[64])smem;
  auto sB = (__hip_bfloat16(*)[64])(smem + 16384);
  const int l = tid & 63, w = tid >> 6;
  const int wm = (w & 1) << 6, wn = (w >> 1) << 6;
  const int lr = l & 15;
  const int lk = (l >> 4) << 3;
  const int lrow = (w << 3) + (l >> 3);
  const int lcol = (l & 7) << 3;

  f32x4 acc[4][4];
  #pragma unroll
  for (int i = 0; i < 4; ++i)
    #pragma unroll
    for (int j = 0; j < 4; ++j) acc[i][j] = {0.f, 0.f, 0.f, 0.f};

  for (int k0 = 0; k0 < 512; k0 += 64) {
    #pragma unroll
    for (int rr = 0; rr < 4; ++rr) {
      // A: two 8B UC loads -> LDS (bypasses L1/L2: sees the GRU's UC stores)
      const int ar = m0 + (rr << 5) + lrow;
      const size_t offs = ((size_t)(ar << 9) + k0 + lcol) >> 2;
      ull u0 = __hip_atomic_load(Au + offs, __ATOMIC_RELAXED, __HIP_MEMORY_SCOPE_AGENT);
      ull u1 = __hip_atomic_load(Au + offs + 1, __ATOMIC_RELAXED, __HIP_MEMORY_SCOPE_AGENT);
      int4 av;
      av.x = (int)(unsigned)u0; av.y = (int)(unsigned)(u0 >> 32);
      av.z = (int)(unsigned)u1; av.w = (int)(unsigned)(u1 >> 32);
      *(int4*)&sA[(rr << 5) + lrow][lcol] = av;
      gl_lds16(B + (size_t)(n0 + (rr << 5) + lrow) * 512 + k0 + lcol, &sB[(rr << 5) + (w << 3)][0]);
    }
    __syncthreads();
    #pragma unroll
    for (int kk = 0; kk < 64; kk += 32) {
      short8 aF[4], bF[4];
      #pragma unroll
      for (int ms = 0; ms < 4; ++ms) aF[ms] = *(const short8*)(&sA[wm + (ms << 4) + lr][kk + lk]);
      #pragma unroll
      for (int ns = 0; ns < 4; ++ns) bF[ns] = *(const short8*)(&sB[wn + (ns << 4) + lr][kk + lk]);
      #pragma unroll
      for (int ms = 0; ms < 4; ++ms)
        #pragma unroll
        for (int ns = 0; ns < 4; ++ns)
          acc[ms][ns] = __builtin_amdgcn_mfma_f32_16x16x32_bf16(aF[ms], bF[ns], acc[ms][ns], 0, 0, 0);
    }
    __syncthreads();
  }

  float* sg = (float*)smem + w * 1088;
  const int r2w = l >> 4;
  const int cw = l & 15;
  const int rbase = r2w << 2;
  #pragma unroll
  for (int ms = 0; ms < 4; ++ms) {
    #pragma unroll
    for (int ns = 0; ns < 4; ++ns)
      #pragma unroll
      for (int r = 0; r < 4; ++r) sg[(rbase + r) * 68 + (ns << 4) + lr] = acc[ms][ns][r];
    #pragma unroll
    for (int qq = 0; qq < 4; ++qq) {
      const int srow2 = (qq << 2) + r2w;
      float4 v = *(const float4*)&sg[srow2 * 68 + (cw << 2)];
      const int r2a = m0 + wm + (ms << 4) + srow2;          // [t][b] row
      const int mrow = ((r2a & 31) << 6) + (r2a >> 5);      // final row b*64+t
      const int col = n0 + wn + (cw << 2);
      float4 b1 = *(const float4*)&out_b[col];
      v.x += b1.x; v.y += b1.y; v.z += b1.z; v.w += b1.w;
      float m4 = fmaxf(fmaxf(v.x, v.y), fmaxf(v.z, v.w));
      #pragma unroll
      for (int hop = 1; hop < 16; hop <<= 1) m4 = fmaxf(m4, __shfl_xor(m4, hop));
      float e = __expf(v.x - m4) + __expf(v.y - m4) + __expf(v.z - m4) + __expf(v.w - m4);
      #pragma unroll
      for (int hop = 1; hop < 16; hop <<= 1) e += __shfl_xor(e, hop);
      if (cw == 0) partials[(size_t)mrow * 500 + ((n0 >> 6) + (wn >> 6))] = make_float2(m4, e);
      if (bfOut) {
        union { __hip_bfloat16 h[4]; uint2 u; } o;
        o.h[0] = __float2bfloat16(v.x);
        o.h[1] = __float2bfloat16(v.y);
        o.h[2] = __float2bfloat16(v.z);
        o.h[3] = __float2bfloat16(v.w);
        *(uint2*)&outBf[(size_t)mrow * Vv + col] = o.u;
      } else {
        *(float4*)&outF[(size_t)mrow * Vv + col] = v;
      }
    }
  }
}

// ---------------- FUSED: encoder GRU (0-127) || dec_xp GEMM (128-223) || outW cvt (224-239) ----------------
__global__ __launch_bounds__(512, 1) void enc_fused_k(
    const float* __restrict__ enc_xp, const uint2* __restrict__ whhB_e,
    const float* __restrict__ enc_bhh, ull* __restrict__ hTag_e,
    const __hip_bfloat16* __restrict__ decX_bf, const __hip_bfloat16* __restrict__ decWih_bf,
    float* __restrict__ dec_xp,
    const float* __restrict__ out_W, __hip_bfloat16* __restrict__ outW_bf) {
  __shared__ __align__(16) char smem[65536];
  const int blk = blockIdx.x;
  if (blk < 128) {
    gru_core(blk & 15, blk >> 4, enc_xp, whhB_e, enc_bhh, hTag_e, nullptr, nullptr, smem,
             nullptr, nullptr, nullptr);
  } else if (blk < 224) {
    const int half = threadIdx.x >> 8;
    const int tile = ((blk - 128) << 1) + half;         // 0..191
    const int m0 = (tile & 15) << 7;
    const int n0 = (tile >> 4) << 7;
    gemm_tile_core(threadIdx.x & 255, m0, n0, decX_bf, decWih_bf, dec_xp,
                   512, 1024, G3, 512, smem + (half << 15));
  } else {
    const int n4 = Vv * Hh / 4;
    for (int i = ((blk - 224) << 9) + threadIdx.x; i < n4; i += 16 * 512) {
      float4 v = ((const float4*)out_W)[i];
      union { __hip_bfloat16 h[4]; uint2 u; } o;
      o.h[0] = __float2bfloat16(v.x);
      o.h[1] = __float2bfloat16(v.y);
      o.h[2] = __float2bfloat16(v.z);
      o.h[3] = __float2bfloat16(v.w);
      ((uint2*)outW_bf)[i] = o.u;
    }
  }
}

// ---------------- FUSED: decoder GRU (blocks 0-127) || logits GEMM workers (128-255) ----------------
// Workers sweep tiles in ascending-t order, polling doneCnt[t_hi]==128 (UC). Acyclic waits:
// workers wait only on GRU progress; GRU never waits on workers -> deadlock-free. Grid 256
// blocks (<= CU count) for co-residency.
__global__ __launch_bounds__(512, 1) void dec_fused_k(
    const float* __restrict__ dec_xp, const uint2* __restrict__ whhB_d,
    const float* __restrict__ dec_bhh,
    const ull* __restrict__ thoughtTag, const float* __restrict__ dec_Wih,
    const float* __restrict__ dec_bih,
    ull* __restrict__ hTag_d, unsigned* __restrict__ decOutU, unsigned* __restrict__ doneCnt,
    const __hip_bfloat16* __restrict__ outW_bf, const float* __restrict__ out_b,
    float* __restrict__ outF, __hip_bfloat16* __restrict__ logitsBf,
    float2* __restrict__ partials, int bfOut) {
  __shared__ __align__(16) char smem[65536];
  const int blk = blockIdx.x;
  if (blk < 128) {
    gru_core(blk & 15, blk >> 4, dec_xp, whhB_d, dec_bhh, hTag_d, decOutU, doneCnt, smem,
             thoughtTag, dec_Wih, dec_bih);
  } else {
    const int b = blk - 128;
    const int tid = threadIdx.x;
    #pragma unroll 1
    for (int j = 0; j < 16; ++j) {
      const int p = j * 128 + b;           // pair index, covers tiles {2p, 2p+1}
      if (p >= 2000) break;                // 4000 tiles = 2000 pairs
      const int mT = (2 * p + 1) / 250;    // max mTile of the pair (tiles are m-major)
      const int thi = 4 * mT + 3;          // last timestep this pair's rows need
      if (tid == 0) {
        while (__hip_atomic_load(doneCnt + thi, __ATOMIC_RELAXED, __HIP_MEMORY_SCOPE_AGENT) < 128u)
          __builtin_amdgcn_s_sleep(2);
      }
      __syncthreads();
      const int half = tid >> 8;
      const int tile = 2 * p + half;
      gemm_logits_core(tid & 255, (tile / 250) << 7, (tile % 250) << 7,
                       (const ull*)decOutU, outW_bf, out_b, outF, logitsBf,
                       partials, bfOut, smem + (half << 15));
    }
  }
}

// ---------------- final log-softmax (f32 logits in place) ----------------
__global__ __launch_bounds__(256) void lsm_final_k(float* __restrict__ X,
                                                   const float2* __restrict__ P) {
  const int row = blockIdx.x;
  const int tid = threadIdx.x;
  float m = -3.4e38f, s = 0.f;
  for (int j = tid; j < 500; j += 256) {
    float2 p = P[(size_t)row * 500 + j];
    if (p.x > m) { s = s * __expf(m - p.x) + p.y; m = p.x; }
    else         { s += p.y * __expf(p.x - m); }
  }
  #pragma unroll
  for (int off2 = 32; off2 > 0; off2 >>= 1) {
    float mo = __shfl_down(m, off2);
    float so = __shfl_down(s, off2);
    float M = fmaxf(m, mo);
    s = s * __expf(m - M) + so * __expf(mo - M);
    m = M;
  }
  __shared__ float sm[4], ss[4];
  if ((tid & 63) == 0) { sm[tid >> 6] = m; ss[tid >> 6] = s; }
  __syncthreads();
  const float M4 = fmaxf(fmaxf(sm[0], sm[1]), fmaxf(sm[2], sm[3]));
  const float S = ss[0] * __expf(sm[0] - M4) + ss[1] * __expf(sm[1] - M4) +
                  ss[2] * __expf(sm[2] - M4) + ss[3] * __expf(sm[3] - M4);
  const float c = M4 + __logf(S);
  float4* p4 = (float4*)(X + (size_t)row * Vv);
  for (int j = tid; j < Vv / 4; j += 256) {
    float4 v = p4[j];
    v.x -= c; v.y -= c; v.z -= c; v.w -= c;
    p4[j] = v;
  }
}

// ---------------- final log-softmax (bf16 logits -> f32 d_out) ----------------
__global__ __launch_bounds__(256) void lsm_final2_k(float* __restrict__ X,
                                                    const __hip_bfloat16* __restrict__ L,
                                                    const float2* __restrict__ P) {
  const int row = blockIdx.x;
  const int tid = threadIdx.x;
  float m = -3.4e38f, s = 0.f;
  for (int j = tid; j < 500; j += 256) {
    float2 p = P[(size_t)row * 500 + j];
    if (p.x > m) { s = s * __expf(m - p.x) + p.y; m = p.x; }
    else         { s += p.y * __expf(p.x - m); }
  }
  #pragma unroll
  for (int off2 = 32; off2 > 0; off2 >>= 1) {
    float mo = __shfl_down(m, off2);
    float so = __shfl_down(s, off2);
    float M = fmaxf(m, mo);
    s = s * __expf(m - M) + so * __expf(mo - M);
    m = M;
  }
  __shared__ float sm[4], ss[4];
  if ((tid & 63) == 0) { sm[tid >> 6] = m; ss[tid >> 6] = s; }
  __syncthreads();
  const float M4 = fmaxf(fmaxf(sm[0], sm[1]), fmaxf(sm[2], sm[3]));
  const float S = ss[0] * __expf(sm[0] - M4) + ss[1] * __expf(sm[1] - M4) +
                  ss[2] * __expf(sm[2] - M4) + ss[3] * __expf(sm[3] - M4);
  const float c = M4 + __logf(S);
  const short8* p8 = (const short8*)(L + (size_t)row * Vv);
  float4* o4 = (float4*)(X + (size_t)row * Vv);
  for (int j = tid; j < Vv / 8; j += 256) {
    short8 sv = p8[j];
    float4 a, b;
    a.x = __uint_as_float(((unsigned)(unsigned short)sv[0]) << 16) - c;
    a.y = __uint_as_float(((unsigned)(unsigned short)sv[1]) << 16) - c;
    a.z = __uint_as_float(((unsigned)(unsigned short)sv[2]) << 16) - c;
    a.w = __uint_as_float(((unsigned)(unsigned short)sv[3]) << 16) - c;
    b.x = __uint_as_float(((unsigned)(unsigned short)sv[4]) << 16) - c;
    b.y = __uint_as_float(((unsigned)(unsigned short)sv[5]) << 16) - c;
    b.z = __uint_as_float(((unsigned)(unsigned short)sv[6]) << 16) - c;
    b.w = __uint_as_float(((unsigned)(unsigned short)sv[7]) << 16) - c;
    o4[(j << 1)] = a;
    o4[(j << 1) + 1] = b;
  }
}

}  // namespace

extern "C" void kernel_launch(void* const* d_in, const int* in_sizes, int n_in,
                              void* d_out, int out_size, void* d_ws, size_t ws_size,
                              hipStream_t stream) {
  (void)in_sizes; (void)n_in; (void)out_size;
  const int*   in_seq  = (const int*)d_in[0];
  const int*   tgt_seq = (const int*)d_in[1];
  const float* enc_emb = (const float*)d_in[2];
  const float* enc_Wih = (const float*)d_in[3];
  const float* enc_Whh = (const float*)d_in[4];
  const float* enc_bih = (const float*)d_in[5];
  const float* enc_bhh = (const float*)d_in[6];
  const float* dec_emb = (const float*)d_in[7];
  const float* dec_Wih = (const float*)d_in[8];
  const float* dec_Whh = (const float*)d_in[9];
  const float* dec_bih = (const float*)d_in[10];
  const float* dec_bhh = (const float*)d_in[11];
  const float* out_W   = (const float*)d_in[12];
  const float* out_b   = (const float*)d_in[13];
  float* out = (float*)d_out;

  char* ws = (char*)d_ws;
  size_t off = 0;
  auto alloc = [&](size_t bytes) -> void* {
    void* p = (void*)(ws + off);
    off += (bytes + 255) & ~(size_t)255;
    return p;
  };
  uint2* whhB_e            = (uint2*)alloc((size_t)512 * 512 * 8);
  uint2* whhB_d            = (uint2*)alloc((size_t)512 * 512 * 8);
  __hip_bfloat16* encWih_bf = (__hip_bfloat16*)alloc((size_t)1536 * 512 * 2);
  __hip_bfloat16* decWih_bf = (__hip_bfloat16*)alloc((size_t)1536 * 1024 * 2);
  __hip_bfloat16* outW_bf   = (__hip_bfloat16*)alloc((size_t)32000 * 512 * 2);
  __hip_bfloat16* encX_bf   = (__hip_bfloat16*)alloc((size_t)2048 * 512 * 2);
  __hip_bfloat16* decX_bf   = (__hip_bfloat16*)alloc((size_t)2048 * 512 * 2);
  float* enc_xp            = (float*)alloc((size_t)2048 * 1536 * 4);
  float* dec_xp            = (float*)alloc((size_t)2048 * 1536 * 4);
  ull* hTag_e              = (ull*)alloc((size_t)2 * 32 * 512 * 8);   // 256KB
  ull* hTag_d              = (ull*)alloc((size_t)2 * 32 * 512 * 8);   // 256KB (contiguous after hTag_e)
  unsigned* doneCnt        = (unsigned*)alloc((size_t)64 * 4);        // contiguous after hTag_d
  unsigned* decOutU        = (unsigned*)alloc((size_t)2048 * 512 * 2);// 2MB packed bf16 [t][b]
  float2* partials         = (float2*)alloc((size_t)2048 * 500 * 8);  // 8.2MB
  __hip_bfloat16* logitsBf  = (__hip_bfloat16*)alloc((size_t)2048 * Vv * 2);  // 131MB (optional)
  const bool bfLogits = (off <= ws_size);

  // --- merged preprocessing: cvt x2 | pack x2 | zero hTag_e+hTag_d+doneCnt ---
  prep_k<<<2689, 256, 0, stream>>>(enc_Wih, encWih_bf, dec_Wih, decWih_bf,
                                   enc_Whh, whhB_e, dec_Whh, whhB_d, (uint4*)hTag_e);

  // --- embeddings ---
  embed_k<<<2048, 128, 0, stream>>>(in_seq, enc_emb, encX_bf, 0);
  embed_k<<<2048, 128, 0, stream>>>(tgt_seq, dec_emb, decX_bf, 1);

  // --- encoder xp = enc_x @ Wih^T + bih : [2048,1536] ---
  gemm_bf16_k<<<192, 256, 0, stream>>>(encX_bf, encWih_bf, enc_xp,
                                       512, 512, G3, 512, enc_bih, 16);

  // --- FUSED: encoder GRU || dec_xp partial GEMM || outW bf16 cvt ---
  enc_fused_k<<<240, 512, 0, stream>>>(enc_xp, whhB_e, enc_bhh, hTag_e,
                                       decX_bf, decWih_bf, dec_xp, out_W, outW_bf);
  // thought = h(64) w/ tag 64 lives in hTag_e buffer 0

  // --- FUSED: decoder GRU || logits GEMM (t-ordered tiles, doneCnt-gated) ---
  dec_fused_k<<<256, 512, 0, stream>>>(dec_xp, whhB_d, dec_bhh,
                                       hTag_e, dec_Wih, dec_bih,
                                       hTag_d, decOutU, doneCnt,
                                       outW_bf, out_b,
                                       out, logitsBf, partials, bfLogits ? 1 : 0);

  // --- final log-softmax ---
  if (bfLogits) {
    lsm_final2_k<<<2048, 256, 0, stream>>>(out, logitsBf, partials);
  } else {
    lsm_final_k<<<2048, 256, 0, stream>>>(out, partials);
  }
}

// Round 15
// 825.748 us; speedup vs baseline: 1.0747x; 1.0747x over previous
//
#include <hip/hip_runtime.h>
#include <hip/hip_bf16.h>
#include <cstdint>
#include <cstddef>

namespace {

constexpr int Hh = 512;
constexpr int G3 = 1536;   // 3*H
constexpr int Bb = 32;
constexpr int Tt = 64;
constexpr int Vv = 32000;

typedef __attribute__((ext_vector_type(8))) short short8;
typedef __attribute__((ext_vector_type(4))) float f32x4;
typedef unsigned long long ull;

__device__ __forceinline__ unsigned bf16bits(float f) {
  union { __hip_bfloat16 h; unsigned short u; } c;
  c.h = __float2bfloat16(f);
  return (unsigned)c.u;
}

// async global->LDS, 16B per lane; LDS dest = wave-uniform base + lane*16
__device__ __forceinline__ void gl_lds16(const void* g, void* l) {
  __builtin_amdgcn_global_load_lds(
      (const __attribute__((address_space(1))) unsigned int*)g,
      (__attribute__((address_space(3))) unsigned int*)l, 16, 0, 0);
}

// ---------------- merged preprocessing: cvt x2 | pack x2 | zero hTag_e+hTag_d+doneCnt ----------------
__device__ __forceinline__ void cvt_range(const float* __restrict__ src,
                                          __hip_bfloat16* __restrict__ dst, int i, int n4) {
  if (i >= n4) return;
  float4 v = ((const float4*)src)[i];
  union { __hip_bfloat16 h[4]; uint2 u; } o;
  o.h[0] = __float2bfloat16(v.x);
  o.h[1] = __float2bfloat16(v.y);
  o.h[2] = __float2bfloat16(v.z);
  o.h[3] = __float2bfloat16(v.w);
  ((uint2*)dst)[i] = o.u;
}

__device__ __forceinline__ void pack_whh_core(const float* __restrict__ Whh,
                                              uint2* __restrict__ P, int k0, int i0) {
  __shared__ float tw[3][32][65];
  const int t = threadIdx.x;               // 256
  const int kk = t & 63, r4 = t >> 6;
  for (int ri = r4; ri < 96; ri += 4) {
    const int g = ri >> 5, ii = ri & 31;
    tw[g][ii][kk] = Whh[(size_t)(g * 512 + i0 + ii) * 512 + k0 + kk];
  }
  __syncthreads();
  const int ii = t & 31, kq = t >> 5;
  for (int k2 = kq; k2 < 64; k2 += 8) {
    unsigned rb = bf16bits(tw[0][ii][k2]);
    unsigned zb = bf16bits(tw[1][ii][k2]);
    unsigned nb = bf16bits(tw[2][ii][k2]);
    P[(size_t)(k0 + k2) * 512 + i0 + ii] = make_uint2((zb << 16) | rb, nb);
  }
}

__global__ __launch_bounds__(256) void prep_k(
    const float* __restrict__ enc_Wih, __hip_bfloat16* __restrict__ encWih_bf,
    const float* __restrict__ dec_Wih, __hip_bfloat16* __restrict__ decWih_bf,
    const float* __restrict__ enc_Whh, uint2* __restrict__ whhB_e,
    const float* __restrict__ dec_Whh, uint2* __restrict__ whhB_d,
    uint4* __restrict__ zeroBase) {
  const int blk = blockIdx.x;
  if (blk < 768) {
    cvt_range(enc_Wih, encWih_bf, blk * 256 + threadIdx.x, 1536 * 512 / 4);
  } else if (blk < 2304) {
    cvt_range(dec_Wih, decWih_bf, (blk - 768) * 256 + threadIdx.x, 1536 * 1024 / 4);
  } else if (blk < 2432) {
    const int b = blk - 2304;
    pack_whh_core(enc_Whh, whhB_e, (b & 7) * 64, (b >> 3) * 32);
  } else if (blk < 2560) {
    const int b = blk - 2432;
    pack_whh_core(dec_Whh, whhB_d, (b & 7) * 64, (b >> 3) * 32);
  } else {
    // zero hTag_e + hTag_d + doneCnt (contiguous): 131136 u32 = 32784 uint4
    const int i = (blk - 2560) * 256 + threadIdx.x;
    if (i < 32784) zeroBase[i] = make_uint4(0u, 0u, 0u, 0u);
  }
}

// ---------------- embedding gather (optionally relu) -> bf16 [2048][512] ----------------
__global__ void embed_k(const int* __restrict__ idx, const float* __restrict__ emb,
                        __hip_bfloat16* __restrict__ outp, int do_relu) {
  int row = blockIdx.x;            // 0..2047 (= b*64+t)
  int r = idx[row];
  float4 v = ((const float4*)(emb + (size_t)r * Hh))[threadIdx.x];  // 128 thr * 4
  if (do_relu) {
    v.x = fmaxf(v.x, 0.f); v.y = fmaxf(v.y, 0.f);
    v.z = fmaxf(v.z, 0.f); v.w = fmaxf(v.w, 0.f);
  }
  union { __hip_bfloat16 h[4]; uint2 u; } o;
  o.h[0] = __float2bfloat16(v.x);
  o.h[1] = __float2bfloat16(v.y);
  o.h[2] = __float2bfloat16(v.z);
  o.h[3] = __float2bfloat16(v.w);
  ((uint2*)(outp + (size_t)row * Hh))[threadIdx.x] = o.u;
}

// ---------------- bf16 MFMA GEMM (standalone, f32 out + bias): used for enc_xp only ----------------
__global__ __launch_bounds__(256) void gemm_bf16_k(
    const __hip_bfloat16* __restrict__ A,
    const __hip_bfloat16* __restrict__ B,
    float* __restrict__ C,
    int lda, int ldb, int ldc, int K,
    const float* __restrict__ bias1,
    int ntm) {
  __shared__ __align__(16) char smem[32768];
  auto sA = (__hip_bfloat16(*)[64])smem;            // [128][64]
  auto sB = (__hip_bfloat16(*)[64])(smem + 16384);  // [128][64]

  const unsigned nwg = gridDim.x, gid = blockIdx.x;
  const unsigned q = nwg >> 3, r8 = nwg & 7, xc = gid & 7, jj = gid >> 3;
  const unsigned wg = (xc < r8 ? xc * (q + 1) : r8 * (q + 1) + (xc - r8) * q) + jj;
  const int m0 = (int)(wg % (unsigned)ntm) << 7;
  const int n0 = (int)(wg / (unsigned)ntm) << 7;

  const int tid = threadIdx.x;
  const int l = tid & 63, w = tid >> 6;
  const int wm = (w & 1) << 6, wn = (w >> 1) << 6;
  const int lr = l & 15;
  const int lk = (l >> 4) << 3;
  const int lrow = (w << 3) + (l >> 3);
  const int lcol = (l & 7) << 3;

  f32x4 acc[4][4];
  #pragma unroll
  for (int i = 0; i < 4; ++i)
    #pragma unroll
    for (int j = 0; j < 4; ++j) acc[i][j] = {0.f, 0.f, 0.f, 0.f};

  for (int k0 = 0; k0 < K; k0 += 64) {
    #pragma unroll
    for (int rr = 0; rr < 4; ++rr) {
      gl_lds16(A + (size_t)(m0 + (rr << 5) + lrow) * lda + k0 + lcol, &sA[(rr << 5) + (w << 3)][0]);
      gl_lds16(B + (size_t)(n0 + (rr << 5) + lrow) * ldb + k0 + lcol, &sB[(rr << 5) + (w << 3)][0]);
    }
    __syncthreads();
    #pragma unroll
    for (int kk = 0; kk < 64; kk += 32) {
      short8 aF[4], bF[4];
      #pragma unroll
      for (int ms = 0; ms < 4; ++ms) aF[ms] = *(const short8*)(&sA[wm + (ms << 4) + lr][kk + lk]);
      #pragma unroll
      for (int ns = 0; ns < 4; ++ns) bF[ns] = *(const short8*)(&sB[wn + (ns << 4) + lr][kk + lk]);
      #pragma unroll
      for (int ms = 0; ms < 4; ++ms)
        #pragma unroll
        for (int ns = 0; ns < 4; ++ns)
          acc[ms][ns] = __builtin_amdgcn_mfma_f32_16x16x32_bf16(aF[ms], bF[ns], acc[ms][ns], 0, 0, 0);
    }
    __syncthreads();
  }

  float* sg = (float*)smem + w * 1088;
  const int r2w = l >> 4;
  const int cw = l & 15;
  const int rbase = r2w << 2;
  #pragma unroll
  for (int ms = 0; ms < 4; ++ms) {
    #pragma unroll
    for (int ns = 0; ns < 4; ++ns)
      #pragma unroll
      for (int r = 0; r < 4; ++r) sg[(rbase + r) * 68 + (ns << 4) + lr] = acc[ms][ns][r];
    #pragma unroll
    for (int qq = 0; qq < 4; ++qq) {
      const int srow2 = (qq << 2) + r2w;
      float4 v = *(const float4*)&sg[srow2 * 68 + (cw << 2)];
      const int row = m0 + wm + (ms << 4) + srow2;
      const int col = n0 + wn + (cw << 2);
      if (bias1) {
        float4 b1 = *(const float4*)&bias1[col];
        v.x += b1.x; v.y += b1.y; v.z += b1.z; v.w += b1.w;
      }
      *(float4*)&C[(size_t)row * ldc + col] = v;
    }
  }
}

// ---------------- GRU core (v5 protocol, proven) + reg-hoisted bhh/tp; [t][b] UC dec_out + doneCnt ----------------
__device__ __forceinline__ void gru_core(
    const int slice, const int bg,
    const float* __restrict__ xp, const uint2* __restrict__ whhB,
    const float* __restrict__ bhh,
    ull* __restrict__ hTag, unsigned* __restrict__ decOutU,  // null or u32-packed bf16 [2048*512/2], row r2=t*32+bb
    unsigned* __restrict__ doneCnt,                          // null or [64]
    char* smem,
    const ull* __restrict__ thoughtTag,   // null or encoder hTag buf0 (thought w/ tag 64)
    const float* __restrict__ decWih,     // f32 [1536][1024] (only if thoughtTag)
    const float* __restrict__ dec_bih) {  // f32 [1536]       (only if thoughtTag)
  float* sH = (float*)smem;                 // 2048 f32 (8KB)
  float* sRed = (float*)(smem + 8192);      // 512*13 f32 (26.6KB)
  const int tid = threadIdx.x;
  const int i0 = slice << 5;
  const int il = tid & 31, kc = tid >> 5;   // 32 i x 16 k-chunks(32k each)
  const int kb0 = kc << 5;

  // ---- step-invariant weights -> 96 VGPRs ----
  float wrF[32], wzF[32], wnF[32];
  {
    const uint2* wp = whhB + i0 + il;
    #pragma unroll
    for (int k4 = 0; k4 < 8; ++k4) {
      #pragma unroll
      for (int j = 0; j < 4; ++j) {
        const int idx = (k4 << 2) + j;
        uint2 wv = wp[(size_t)(kb0 + idx) << 9];
        wrF[idx] = __uint_as_float(wv.x << 16);
        wzF[idx] = __uint_as_float(wv.x & 0xffff0000u);
        wnF[idx] = __uint_as_float(wv.y << 16);
      }
    }
  }

  // ---- tail invariants: bhh, tp (thought projection) ----
  float bh_r = 0.f, bh_z = 0.f, bh_n = 0.f;
  float tpr = 0.f, tpz = 0.f, tpn = 0.f;
  int gi = 0, bb = 0;
  if (tid < 128) {
    const int b = tid >> 5, i2 = tid & 31;
    gi = i0 + i2;
    bb = (bg << 2) + b;
    bh_r = bhh[gi]; bh_z = bhh[512 + gi]; bh_n = bhh[1024 + gi];
  }
  if (thoughtTag) {
    #pragma unroll
    for (int j = 0; j < 4; ++j) {
      ull v = __hip_atomic_load(thoughtTag + ((size_t)bg << 11) + (j << 9) + tid,
                                __ATOMIC_RELAXED, __HIP_MEMORY_SCOPE_AGENT);
      sH[(j << 9) + tid] = fmaxf(__uint_as_float((unsigned)v), 0.f);
    }
    __syncthreads();
    if (tid < 384) {
      const int b = tid / 96, j = tid % 96;
      const int g = j >> 5, i2 = j & 31;
      const int row = g * 512 + i0 + i2;
      const float4* w4 = (const float4*)(decWih + (size_t)row * 1024 + 512);
      const float* th = &sH[b << 9];
      float s = dec_bih[row];
      #pragma unroll 4
      for (int k = 0; k < 128; ++k) {
        float4 w = w4[k];
        float4 t4 = *(const float4*)&th[k << 2];
        s += w.x * t4.x + w.y * t4.y + w.z * t4.z + w.w * t4.w;
      }
      sRed[tid] = s;
    }
    __syncthreads();
    if (tid < 128) {
      const int b = tid >> 5, i2 = tid & 31;
      tpr = sRed[b * 96 + i2];
      tpz = sRed[b * 96 + 32 + i2];
      tpn = sRed[b * 96 + 64 + i2];
    }
    __syncthreads();
  }

  #pragma unroll 1
  for (int t = 0; t < Tt; ++t) {
    // poll + load h(t) (tag word = {step<<32 | f32}, buffer = t parity)
    {
      const ull* hb = hTag + ((size_t)(t & 1) << 14) + ((size_t)bg << 11);
      #pragma unroll
      for (int j = 0; j < 4; ++j) {
        const ull* p = hb + (j << 9) + tid;
        ull v = __hip_atomic_load(p, __ATOMIC_RELAXED, __HIP_MEMORY_SCOPE_AGENT);
        while ((unsigned)(v >> 32) != (unsigned)t) {
          __builtin_amdgcn_s_sleep(1);
          v = __hip_atomic_load(p, __ATOMIC_RELAXED, __HIP_MEMORY_SCOPE_AGENT);
        }
        sH[(j << 9) + tid] = __uint_as_float((unsigned)v);
      }
    }
    __syncthreads();   // B0

    float a[12];
    #pragma unroll
    for (int v = 0; v < 12; ++v) a[v] = 0.f;
    #pragma unroll
    for (int k4 = 0; k4 < 8; ++k4) {
      const int kb = kb0 + (k4 << 2);
      float4 hv0 = *(const float4*)&sH[kb];
      float4 hv1 = *(const float4*)&sH[512 + kb];
      float4 hv2 = *(const float4*)&sH[1024 + kb];
      float4 hv3 = *(const float4*)&sH[1536 + kb];
      const float* h0p = (const float*)&hv0;
      const float* h1p = (const float*)&hv1;
      const float* h2p = (const float*)&hv2;
      const float* h3p = (const float*)&hv3;
      #pragma unroll
      for (int j = 0; j < 4; ++j) {
        const int idx = (k4 << 2) + j;
        const float wr = wrF[idx], wz = wzF[idx], wn = wnF[idx];
        a[0]  = fmaf(wr, h0p[j], a[0]);  a[1]  = fmaf(wz, h0p[j], a[1]);  a[2]  = fmaf(wn, h0p[j], a[2]);
        a[3]  = fmaf(wr, h1p[j], a[3]);  a[4]  = fmaf(wz, h1p[j], a[4]);  a[5]  = fmaf(wn, h1p[j], a[5]);
        a[6]  = fmaf(wr, h2p[j], a[6]);  a[7]  = fmaf(wz, h2p[j], a[7]);  a[8]  = fmaf(wn, h2p[j], a[8]);
        a[9]  = fmaf(wr, h3p[j], a[9]);  a[10] = fmaf(wz, h3p[j], a[10]); a[11] = fmaf(wn, h3p[j], a[11]);
      }
    }
    {
      float* red = &sRed[tid * 13];
      #pragma unroll
      for (int v = 0; v < 12; ++v) red[v] = a[v];
    }
    __syncthreads();   // B1

    if (tid < 128) {
      const int b = tid >> 5, i2 = tid & 31;
      float s0 = 0.f, s1 = 0.f, s2 = 0.f;
      #pragma unroll
      for (int kc2 = 0; kc2 < 16; ++kc2) {
        const float* rp = &sRed[(kc2 * 32 + i2) * 13 + b * 3];
        s0 += rp[0]; s1 += rp[1]; s2 += rp[2];
      }
      const float hr = s0 + bh_r;
      const float hz = s1 + bh_z;
      const float hn = s2 + bh_n;
      const size_t m = (size_t)bb * Tt + t;
      const float xr = xp[m * G3 + gi] + tpr;
      const float xz = xp[m * G3 + 512 + gi] + tpz;
      const float xn = xp[m * G3 + 1024 + gi] + tpn;
      const float rg = 1.f / (1.f + __expf(-(xr + hr)));
      const float zg = 1.f / (1.f + __expf(-(xz + hz)));
      const float ng = tanhf(xn + rg * hn);
      const float hnew = (1.f - zg) * ng + zg * sH[(b << 9) + gi];
      ull* dst = hTag + ((size_t)((t + 1) & 1) << 14) + ((size_t)bb << 9) + gi;
      __hip_atomic_store(dst, ((ull)(unsigned)(t + 1) << 32) | (ull)__float_as_uint(hnew),
                         __ATOMIC_RELAXED, __HIP_MEMORY_SCOPE_AGENT);
      if (decOutU) {
        // [t][b] layout, UC paired-u32 store: row r2=t*32+bb, col gi; even lane packs (gi, gi+1)
        unsigned bbits = bf16bits(hnew);
        unsigned pbits = __shfl_down(bbits, 1);
        if (!(tid & 1)) {
          const int r2 = (t << 5) + bb;
          __hip_atomic_store(decOutU + (((r2 << 9) + gi) >> 1), (pbits << 16) | bbits,
                             __ATOMIC_RELAXED, __HIP_MEMORY_SCOPE_AGENT);
        }
      }
    }
    __syncthreads();   // B2: drains UC stores (vmcnt 0) before flag
    if (doneCnt && tid == 0) {
      __hip_atomic_fetch_add(doneCnt + t, 1u, __ATOMIC_RELAXED, __HIP_MEMORY_SCOPE_AGENT);
    }
  }
}

// ---------------- 128x128 tile GEMM core (cached A+B, f32 out) for enc_fused dec_xp ----------------
__device__ __forceinline__ void gemm_tile_core(
    const int tid, const int m0, const int n0,
    const __hip_bfloat16* __restrict__ A, const __hip_bfloat16* __restrict__ B,
    float* __restrict__ C, int lda, int ldb, int ldc, int K, char* smem) {
  auto sA = (__hip_bfloat16(*)[64])smem;
  auto sB = (__hip_bfloat16(*)[64])(smem + 16384);
  const int l = tid & 63, w = tid >> 6;
  const int wm = (w & 1) << 6, wn = (w >> 1) << 6;
  const int lr = l & 15;
  const int lk = (l >> 4) << 3;
  const int lrow = (w << 3) + (l >> 3);
  const int lcol = (l & 7) << 3;

  f32x4 acc[4][4];
  #pragma unroll
  for (int i = 0; i < 4; ++i)
    #pragma unroll
    for (int j = 0; j < 4; ++j) acc[i][j] = {0.f, 0.f, 0.f, 0.f};

  for (int k0 = 0; k0 < K; k0 += 64) {
    #pragma unroll
    for (int rr = 0; rr < 4; ++rr) {
      gl_lds16(A + (size_t)(m0 + (rr << 5) + lrow) * lda + k0 + lcol, &sA[(rr << 5) + (w << 3)][0]);
      gl_lds16(B + (size_t)(n0 + (rr << 5) + lrow) * ldb + k0 + lcol, &sB[(rr << 5) + (w << 3)][0]);
    }
    __syncthreads();
    #pragma unroll
    for (int kk = 0; kk < 64; kk += 32) {
      short8 aF[4], bF[4];
      #pragma unroll
      for (int ms = 0; ms < 4; ++ms) aF[ms] = *(const short8*)(&sA[wm + (ms << 4) + lr][kk + lk]);
      #pragma unroll
      for (int ns = 0; ns < 4; ++ns) bF[ns] = *(const short8*)(&sB[wn + (ns << 4) + lr][kk + lk]);
      #pragma unroll
      for (int ms = 0; ms < 4; ++ms)
        #pragma unroll
        for (int ns = 0; ns < 4; ++ns)
          acc[ms][ns] = __builtin_amdgcn_mfma_f32_16x16x32_bf16(aF[ms], bF[ns], acc[ms][ns], 0, 0, 0);
    }
    __syncthreads();
  }

  float* sg = (float*)smem + w * 1088;
  const int r2w = l >> 4;
  const int cw = l & 15;
  const int rbase = r2w << 2;
  #pragma unroll
  for (int ms = 0; ms < 4; ++ms) {
    #pragma unroll
    for (int ns = 0; ns < 4; ++ns)
      #pragma unroll
      for (int r = 0; r < 4; ++r) sg[(rbase + r) * 68 + (ns << 4) + lr] = acc[ms][ns][r];
    #pragma unroll
    for (int qq = 0; qq < 4; ++qq) {
      const int srow2 = (qq << 2) + r2w;
      float4 v = *(const float4*)&sg[srow2 * 68 + (cw << 2)];
      *(float4*)&C[(size_t)(m0 + wm + (ms << 4) + srow2) * ldc + n0 + wn + (cw << 2)] = v;
    }
  }
}

// ---------------- logits tile core: A via CACHED global_load_lds (round-15 fix) ----------------
// Coherence: per-XCD L2 is invalidated at dispatch start (empirically relied on by rounds
// 8-13: UC-stored hTag read with cached loads cross-kernel). decOutU lines are write-once
// (UC, to LLC) and first READ strictly after the doneCnt gate -> a cached read cannot
// observe a pre-write copy; after first touch the line is immutable for the replay.
// Output rows remapped r2->m=(bb<<6)+t in epilogue; emits partials + bf16/f32 logits.
__device__ __forceinline__ void gemm_logits_core(
    const int tid, const int m0, const int n0,
    const __hip_bfloat16* __restrict__ Abf,  // decOut bf16, [t][b] rows, lda=512
    const __hip_bfloat16* __restrict__ B,    // outW_bf [32000][512]
    const float* __restrict__ out_b,
    float* __restrict__ outF, __hip_bfloat16* __restrict__ outBf,
    float2* __restrict__ partials, const int bfOut, char* smem) {
  auto sA = (__hip_bfloat16(*)[64])smem;
  auto sB = (__hip_bfloat16(*)[64])(smem + 16384);
  const int l = tid & 63, w = tid >> 6;
  const int wm = (w & 1) << 6, wn = (w >> 1) << 6;
  const int lr = l & 15;
  const int lk = (l >> 4) << 3;
  const int lrow = (w << 3) + (l >> 3);
  const int lcol = (l & 7) << 3;

  f32x4 acc[4][4];
  #pragma unroll
  for (int i = 0; i < 4; ++i)
    #pragma unroll
    for (int j = 0; j < 4; ++j) acc[i][j] = {0.f, 0.f, 0.f, 0.f};

  for (int k0 = 0; k0 < 512; k0 += 64) {
    #pragma unroll
    for (int rr = 0; rr < 4; ++rr) {
      gl_lds16(Abf + (size_t)(m0 + (rr << 5) + lrow) * 512 + k0 + lcol, &sA[(rr << 5) + (w << 3)][0]);
      gl_lds16(B + (size_t)(n0 + (rr << 5) + lrow) * 512 + k0 + lcol, &sB[(rr << 5) + (w << 3)][0]);
    }
    __syncthreads();
    #pragma unroll
    for (int kk = 0; kk < 64; kk += 32) {
      short8 aF[4], bF[4];
      #pragma unroll
      for (int ms = 0; ms < 4; ++ms) aF[ms] = *(const short8*)(&sA[wm + (ms << 4) + lr][kk + lk]);
      #pragma unroll
      for (int ns = 0; ns < 4; ++ns) bF[ns] = *(const short8*)(&sB[wn + (ns << 4) + lr][kk + lk]);
      #pragma unroll
      for (int ms = 0; ms < 4; ++ms)
        #pragma unroll
        for (int ns = 0; ns < 4; ++ns)
          acc[ms][ns] = __builtin_amdgcn_mfma_f32_16x16x32_bf16(aF[ms], bF[ns], acc[ms][ns], 0, 0, 0);
    }
    __syncthreads();
  }

  float* sg = (float*)smem + w * 1088;
  const int r2w = l >> 4;
  const int cw = l & 15;
  const int rbase = r2w << 2;
  #pragma unroll
  for (int ms = 0; ms < 4; ++ms) {
    #pragma unroll
    for (int ns = 0; ns < 4; ++ns)
      #pragma unroll
      for (int r = 0; r < 4; ++r) sg[(rbase + r) * 68 + (ns << 4) + lr] = acc[ms][ns][r];
    #pragma unroll
    for (int qq = 0; qq < 4; ++qq) {
      const int srow2 = (qq << 2) + r2w;
      float4 v = *(const float4*)&sg[srow2 * 68 + (cw << 2)];
      const int r2a = m0 + wm + (ms << 4) + srow2;          // [t][b] row
      const int mrow = ((r2a & 31) << 6) + (r2a >> 5);      // final row b*64+t
      const int col = n0 + wn + (cw << 2);
      float4 b1 = *(const float4*)&out_b[col];
      v.x += b1.x; v.y += b1.y; v.z += b1.z; v.w += b1.w;
      float m4 = fmaxf(fmaxf(v.x, v.y), fmaxf(v.z, v.w));
      #pragma unroll
      for (int hop = 1; hop < 16; hop <<= 1) m4 = fmaxf(m4, __shfl_xor(m4, hop));
      float e = __expf(v.x - m4) + __expf(v.y - m4) + __expf(v.z - m4) + __expf(v.w - m4);
      #pragma unroll
      for (int hop = 1; hop < 16; hop <<= 1) e += __shfl_xor(e, hop);
      if (cw == 0) partials[(size_t)mrow * 500 + ((n0 >> 6) + (wn >> 6))] = make_float2(m4, e);
      if (bfOut) {
        union { __hip_bfloat16 h[4]; uint2 u; } o;
        o.h[0] = __float2bfloat16(v.x);
        o.h[1] = __float2bfloat16(v.y);
        o.h[2] = __float2bfloat16(v.z);
        o.h[3] = __float2bfloat16(v.w);
        *(uint2*)&outBf[(size_t)mrow * Vv + col] = o.u;
      } else {
        *(float4*)&outF[(size_t)mrow * Vv + col] = v;
      }
    }
  }
}

// ---------------- FUSED: encoder GRU (0-127) || dec_xp GEMM (128-223) || outW cvt (224-239) ----------------
__global__ __launch_bounds__(512, 1) void enc_fused_k(
    const float* __restrict__ enc_xp, const uint2* __restrict__ whhB_e,
    const float* __restrict__ enc_bhh, ull* __restrict__ hTag_e,
    const __hip_bfloat16* __restrict__ decX_bf, const __hip_bfloat16* __restrict__ decWih_bf,
    float* __restrict__ dec_xp,
    const float* __restrict__ out_W, __hip_bfloat16* __restrict__ outW_bf) {
  __shared__ __align__(16) char smem[65536];
  const int blk = blockIdx.x;
  if (blk < 128) {
    gru_core(blk & 15, blk >> 4, enc_xp, whhB_e, enc_bhh, hTag_e, nullptr, nullptr, smem,
             nullptr, nullptr, nullptr);
  } else if (blk < 224) {
    const int half = threadIdx.x >> 8;
    const int tile = ((blk - 128) << 1) + half;         // 0..191
    const int m0 = (tile & 15) << 7;
    const int n0 = (tile >> 4) << 7;
    gemm_tile_core(threadIdx.x & 255, m0, n0, decX_bf, decWih_bf, dec_xp,
                   512, 1024, G3, 512, smem + (half << 15));
  } else {
    const int n4 = Vv * Hh / 4;
    for (int i = ((blk - 224) << 9) + threadIdx.x; i < n4; i += 16 * 512) {
      float4 v = ((const float4*)out_W)[i];
      union { __hip_bfloat16 h[4]; uint2 u; } o;
      o.h[0] = __float2bfloat16(v.x);
      o.h[1] = __float2bfloat16(v.y);
      o.h[2] = __float2bfloat16(v.z);
      o.h[3] = __float2bfloat16(v.w);
      ((uint2*)outW_bf)[i] = o.u;
    }
  }
}

// ---------------- FUSED: decoder GRU (blocks 0-127) || logits GEMM workers (128-255) ----------------
// Workers sweep tiles in ascending-t order, polling doneCnt[t_hi]==128 (UC). Acyclic waits:
// workers wait only on GRU progress; GRU never waits on workers -> deadlock-free. Grid 256
// blocks (<= CU count) for co-residency.
__global__ __launch_bounds__(512, 1) void dec_fused_k(
    const float* __restrict__ dec_xp, const uint2* __restrict__ whhB_d,
    const float* __restrict__ dec_bhh,
    const ull* __restrict__ thoughtTag, const float* __restrict__ dec_Wih,
    const float* __restrict__ dec_bih,
    ull* __restrict__ hTag_d, unsigned* __restrict__ decOutU, unsigned* __restrict__ doneCnt,
    const __hip_bfloat16* __restrict__ outW_bf, const float* __restrict__ out_b,
    float* __restrict__ outF, __hip_bfloat16* __restrict__ logitsBf,
    float2* __restrict__ partials, int bfOut) {
  __shared__ __align__(16) char smem[65536];
  const int blk = blockIdx.x;
  if (blk < 128) {
    gru_core(blk & 15, blk >> 4, dec_xp, whhB_d, dec_bhh, hTag_d, decOutU, doneCnt, smem,
             thoughtTag, dec_Wih, dec_bih);
  } else {
    const int b = blk - 128;
    const int tid = threadIdx.x;
    #pragma unroll 1
    for (int j = 0; j < 16; ++j) {
      const int p = j * 128 + b;           // pair index, covers tiles {2p, 2p+1}
      if (p >= 2000) break;                // 4000 tiles = 2000 pairs
      const int mT = (2 * p + 1) / 250;    // max mTile of the pair (tiles are m-major)
      const int thi = 4 * mT + 3;          // last timestep this pair's rows need
      if (tid == 0) {
        while (__hip_atomic_load(doneCnt + thi, __ATOMIC_RELAXED, __HIP_MEMORY_SCOPE_AGENT) < 128u)
          __builtin_amdgcn_s_sleep(4);
      }
      __syncthreads();
      const int half = tid >> 8;
      const int tile = 2 * p + half;
      gemm_logits_core(tid & 255, (tile / 250) << 7, (tile % 250) << 7,
                       (const __hip_bfloat16*)decOutU, outW_bf, out_b, outF, logitsBf,
                       partials, bfOut, smem + (half << 15));
    }
  }
}

// ---------------- final log-softmax (f32 logits in place) ----------------
__global__ __launch_bounds__(256) void lsm_final_k(float* __restrict__ X,
                                                   const float2* __restrict__ P) {
  const int row = blockIdx.x;
  const int tid = threadIdx.x;
  float m = -3.4e38f, s = 0.f;
  for (int j = tid; j < 500; j += 256) {
    float2 p = P[(size_t)row * 500 + j];
    if (p.x > m) { s = s * __expf(m - p.x) + p.y; m = p.x; }
    else         { s += p.y * __expf(p.x - m); }
  }
  #pragma unroll
  for (int off2 = 32; off2 > 0; off2 >>= 1) {
    float mo = __shfl_down(m, off2);
    float so = __shfl_down(s, off2);
    float M = fmaxf(m, mo);
    s = s * __expf(m - M) + so * __expf(mo - M);
    m = M;
  }
  __shared__ float sm[4], ss[4];
  if ((tid & 63) == 0) { sm[tid >> 6] = m; ss[tid >> 6] = s; }
  __syncthreads();
  const float M4 = fmaxf(fmaxf(sm[0], sm[1]), fmaxf(sm[2], sm[3]));
  const float S = ss[0] * __expf(sm[0] - M4) + ss[1] * __expf(sm[1] - M4) +
                  ss[2] * __expf(sm[2] - M4) + ss[3] * __expf(sm[3] - M4);
  const float c = M4 + __logf(S);
  float4* p4 = (float4*)(X + (size_t)row * Vv);
  for (int j = tid; j < Vv / 4; j += 256) {
    float4 v = p4[j];
    v.x -= c; v.y -= c; v.z -= c; v.w -= c;
    p4[j] = v;
  }
}

// ---------------- final log-softmax (bf16 logits -> f32 d_out) ----------------
__global__ __launch_bounds__(256) void lsm_final2_k(float* __restrict__ X,
                                                    const __hip_bfloat16* __restrict__ L,
                                                    const float2* __restrict__ P) {
  const int row = blockIdx.x;
  const int tid = threadIdx.x;
  float m = -3.4e38f, s = 0.f;
  for (int j = tid; j < 500; j += 256) {
    float2 p = P[(size_t)row * 500 + j];
    if (p.x > m) { s = s * __expf(m - p.x) + p.y; m = p.x; }
    else         { s += p.y * __expf(p.x - m); }
  }
  #pragma unroll
  for (int off2 = 32; off2 > 0; off2 >>= 1) {
    float mo = __shfl_down(m, off2);
    float so = __shfl_down(s, off2);
    float M = fmaxf(m, mo);
    s = s * __expf(m - M) + so * __expf(mo - M);
    m = M;
  }
  __shared__ float sm[4], ss[4];
  if ((tid & 63) == 0) { sm[tid >> 6] = m; ss[tid >> 6] = s; }
  __syncthreads();
  const float M4 = fmaxf(fmaxf(sm[0], sm[1]), fmaxf(sm[2], sm[3]));
  const float S = ss[0] * __expf(sm[0] - M4) + ss[1] * __expf(sm[1] - M4) +
                  ss[2] * __expf(sm[2] - M4) + ss[3] * __expf(sm[3] - M4);
  const float c = M4 + __logf(S);
  const short8* p8 = (const short8*)(L + (size_t)row * Vv);
  float4* o4 = (float4*)(X + (size_t)row * Vv);
  for (int j = tid; j < Vv / 8; j += 256) {
    short8 sv = p8[j];
    float4 a, b;
    a.x = __uint_as_float(((unsigned)(unsigned short)sv[0]) << 16) - c;
    a.y = __uint_as_float(((unsigned)(unsigned short)sv[1]) << 16) - c;
    a.z = __uint_as_float(((unsigned)(unsigned short)sv[2]) << 16) - c;
    a.w = __uint_as_float(((unsigned)(unsigned short)sv[3]) << 16) - c;
    b.x = __uint_as_float(((unsigned)(unsigned short)sv[4]) << 16) - c;
    b.y = __uint_as_float(((unsigned)(unsigned short)sv[5]) << 16) - c;
    b.z = __uint_as_float(((unsigned)(unsigned short)sv[6]) << 16) - c;
    b.w = __uint_as_float(((unsigned)(unsigned short)sv[7]) << 16) - c;
    o4[(j << 1)] = a;
    o4[(j << 1) + 1] = b;
  }
}

}  // namespace

extern "C" void kernel_launch(void* const* d_in, const int* in_sizes, int n_in,
                              void* d_out, int out_size, void* d_ws, size_t ws_size,
                              hipStream_t stream) {
  (void)in_sizes; (void)n_in; (void)out_size;
  const int*   in_seq  = (const int*)d_in[0];
  const int*   tgt_seq = (const int*)d_in[1];
  const float* enc_emb = (const float*)d_in[2];
  const float* enc_Wih = (const float*)d_in[3];
  const float* enc_Whh = (const float*)d_in[4];
  const float* enc_bih = (const float*)d_in[5];
  const float* enc_bhh = (const float*)d_in[6];
  const float* dec_emb = (const float*)d_in[7];
  const float* dec_Wih = (const float*)d_in[8];
  const float* dec_Whh = (const float*)d_in[9];
  const float* dec_bih = (const float*)d_in[10];
  const float* dec_bhh = (const float*)d_in[11];
  const float* out_W   = (const float*)d_in[12];
  const float* out_b   = (const float*)d_in[13];
  float* out = (float*)d_out;

  char* ws = (char*)d_ws;
  size_t off = 0;
  auto alloc = [&](size_t bytes) -> void* {
    void* p = (void*)(ws + off);
    off += (bytes + 255) & ~(size_t)255;
    return p;
  };
  uint2* whhB_e            = (uint2*)alloc((size_t)512 * 512 * 8);
  uint2* whhB_d            = (uint2*)alloc((size_t)512 * 512 * 8);
  __hip_bfloat16* encWih_bf = (__hip_bfloat16*)alloc((size_t)1536 * 512 * 2);
  __hip_bfloat16* decWih_bf = (__hip_bfloat16*)alloc((size_t)1536 * 1024 * 2);
  __hip_bfloat16* outW_bf   = (__hip_bfloat16*)alloc((size_t)32000 * 512 * 2);
  __hip_bfloat16* encX_bf   = (__hip_bfloat16*)alloc((size_t)2048 * 512 * 2);
  __hip_bfloat16* decX_bf   = (__hip_bfloat16*)alloc((size_t)2048 * 512 * 2);
  float* enc_xp            = (float*)alloc((size_t)2048 * 1536 * 4);
  float* dec_xp            = (float*)alloc((size_t)2048 * 1536 * 4);
  ull* hTag_e              = (ull*)alloc((size_t)2 * 32 * 512 * 8);   // 256KB
  ull* hTag_d              = (ull*)alloc((size_t)2 * 32 * 512 * 8);   // 256KB (contiguous after hTag_e)
  unsigned* doneCnt        = (unsigned*)alloc((size_t)64 * 4);        // contiguous after hTag_d
  unsigned* decOutU        = (unsigned*)alloc((size_t)2048 * 512 * 2);// 2MB packed bf16 [t][b]
  float2* partials         = (float2*)alloc((size_t)2048 * 500 * 8);  // 8.2MB
  __hip_bfloat16* logitsBf  = (__hip_bfloat16*)alloc((size_t)2048 * Vv * 2);  // 131MB (optional)
  const bool bfLogits = (off <= ws_size);

  // --- merged preprocessing: cvt x2 | pack x2 | zero hTag_e+hTag_d+doneCnt ---
  prep_k<<<2689, 256, 0, stream>>>(enc_Wih, encWih_bf, dec_Wih, decWih_bf,
                                   enc_Whh, whhB_e, dec_Whh, whhB_d, (uint4*)hTag_e);

  // --- embeddings ---
  embed_k<<<2048, 128, 0, stream>>>(in_seq, enc_emb, encX_bf, 0);
  embed_k<<<2048, 128, 0, stream>>>(tgt_seq, dec_emb, decX_bf, 1);

  // --- encoder xp = enc_x @ Wih^T + bih : [2048,1536] ---
  gemm_bf16_k<<<192, 256, 0, stream>>>(encX_bf, encWih_bf, enc_xp,
                                       512, 512, G3, 512, enc_bih, 16);

  // --- FUSED: encoder GRU || dec_xp partial GEMM || outW bf16 cvt ---
  enc_fused_k<<<240, 512, 0, stream>>>(enc_xp, whhB_e, enc_bhh, hTag_e,
                                       decX_bf, decWih_bf, dec_xp, out_W, outW_bf);
  // thought = h(64) w/ tag 64 lives in hTag_e buffer 0

  // --- FUSED: decoder GRU || logits GEMM (t-ordered tiles, doneCnt-gated, cached A) ---
  dec_fused_k<<<256, 512, 0, stream>>>(dec_xp, whhB_d, dec_bhh,
                                       hTag_e, dec_Wih, dec_bih,
                                       hTag_d, decOutU, doneCnt,
                                       outW_bf, out_b,
                                       out, logitsBf, partials, bfLogits ? 1 : 0);

  // --- final log-softmax ---
  if (bfLogits) {
    lsm_final2_k<<<2048, 256, 0, stream>>>(out, logitsBf, partials);
  } else {
    lsm_final_k<<<2048, 256, 0, stream>>>(out, partials);
  }
}

// Round 16
// 803.435 us; speedup vs baseline: 1.1045x; 1.0278x over previous
//
#include <hip/hip_runtime.h>
#include <hip/hip_bf16.h>
#include <cstdint>
#include <cstddef>

namespace {

constexpr int Hh = 512;
constexpr int G3 = 1536;   // 3*H
constexpr int Bb = 32;
constexpr int Tt = 64;
constexpr int Vv = 32000;

typedef __attribute__((ext_vector_type(8))) short short8;
typedef __attribute__((ext_vector_type(4))) float f32x4;
typedef unsigned long long ull;

__device__ __forceinline__ unsigned bf16bits(float f) {
  union { __hip_bfloat16 h; unsigned short u; } c;
  c.h = __float2bfloat16(f);
  return (unsigned)c.u;
}

// async global->LDS, 16B per lane; LDS dest = wave-uniform base + lane*16
__device__ __forceinline__ void gl_lds16(const void* g, void* l) {
  __builtin_amdgcn_global_load_lds(
      (const __attribute__((address_space(1))) unsigned int*)g,
      (__attribute__((address_space(3))) unsigned int*)l, 16, 0, 0);
}

// ---------------- merged preprocessing: cvt x2 | pack x2 | zero hTag_e+hTag_d+doneCnt ----------------
__device__ __forceinline__ void cvt_range(const float* __restrict__ src,
                                          __hip_bfloat16* __restrict__ dst, int i, int n4) {
  if (i >= n4) return;
  float4 v = ((const float4*)src)[i];
  union { __hip_bfloat16 h[4]; uint2 u; } o;
  o.h[0] = __float2bfloat16(v.x);
  o.h[1] = __float2bfloat16(v.y);
  o.h[2] = __float2bfloat16(v.z);
  o.h[3] = __float2bfloat16(v.w);
  ((uint2*)dst)[i] = o.u;
}

__device__ __forceinline__ void pack_whh_core(const float* __restrict__ Whh,
                                              uint2* __restrict__ P, int k0, int i0) {
  __shared__ float tw[3][32][65];
  const int t = threadIdx.x;               // 256
  const int kk = t & 63, r4 = t >> 6;
  for (int ri = r4; ri < 96; ri += 4) {
    const int g = ri >> 5, ii = ri & 31;
    tw[g][ii][kk] = Whh[(size_t)(g * 512 + i0 + ii) * 512 + k0 + kk];
  }
  __syncthreads();
  const int ii = t & 31, kq = t >> 5;
  for (int k2 = kq; k2 < 64; k2 += 8) {
    unsigned rb = bf16bits(tw[0][ii][k2]);
    unsigned zb = bf16bits(tw[1][ii][k2]);
    unsigned nb = bf16bits(tw[2][ii][k2]);
    P[(size_t)(k0 + k2) * 512 + i0 + ii] = make_uint2((zb << 16) | rb, nb);
  }
}

__global__ __launch_bounds__(256) void prep_k(
    const float* __restrict__ enc_Wih, __hip_bfloat16* __restrict__ encWih_bf,
    const float* __restrict__ dec_Wih, __hip_bfloat16* __restrict__ decWih_bf,
    const float* __restrict__ enc_Whh, uint2* __restrict__ whhB_e,
    const float* __restrict__ dec_Whh, uint2* __restrict__ whhB_d,
    uint4* __restrict__ zeroBase) {
  const int blk = blockIdx.x;
  if (blk < 768) {
    cvt_range(enc_Wih, encWih_bf, blk * 256 + threadIdx.x, 1536 * 512 / 4);
  } else if (blk < 2304) {
    cvt_range(dec_Wih, decWih_bf, (blk - 768) * 256 + threadIdx.x, 1536 * 1024 / 4);
  } else if (blk < 2432) {
    const int b = blk - 2304;
    pack_whh_core(enc_Whh, whhB_e, (b & 7) * 64, (b >> 3) * 32);
  } else if (blk < 2560) {
    const int b = blk - 2432;
    pack_whh_core(dec_Whh, whhB_d, (b & 7) * 64, (b >> 3) * 32);
  } else {
    // zero hTag_e + hTag_d + doneCnt (contiguous): 131136 u32 = 32784 uint4
    const int i = (blk - 2560) * 256 + threadIdx.x;
    if (i < 32784) zeroBase[i] = make_uint4(0u, 0u, 0u, 0u);
  }
}

// ---------------- embedding gather (optionally relu) -> bf16 [2048][512] ----------------
__global__ void embed_k(const int* __restrict__ idx, const float* __restrict__ emb,
                        __hip_bfloat16* __restrict__ outp, int do_relu) {
  int row = blockIdx.x;            // 0..2047 (= b*64+t)
  int r = idx[row];
  float4 v = ((const float4*)(emb + (size_t)r * Hh))[threadIdx.x];  // 128 thr * 4
  if (do_relu) {
    v.x = fmaxf(v.x, 0.f); v.y = fmaxf(v.y, 0.f);
    v.z = fmaxf(v.z, 0.f); v.w = fmaxf(v.w, 0.f);
  }
  union { __hip_bfloat16 h[4]; uint2 u; } o;
  o.h[0] = __float2bfloat16(v.x);
  o.h[1] = __float2bfloat16(v.y);
  o.h[2] = __float2bfloat16(v.z);
  o.h[3] = __float2bfloat16(v.w);
  ((uint2*)(outp + (size_t)row * Hh))[threadIdx.x] = o.u;
}

// ---------------- bf16 MFMA GEMM (standalone, f32 out + bias): used for enc_xp only ----------------
__global__ __launch_bounds__(256) void gemm_bf16_k(
    const __hip_bfloat16* __restrict__ A,
    const __hip_bfloat16* __restrict__ B,
    float* __restrict__ C,
    int lda, int ldb, int ldc, int K,
    const float* __restrict__ bias1,
    int ntm) {
  __shared__ __align__(16) char smem[32768];
  auto sA = (__hip_bfloat16(*)[64])smem;            // [128][64]
  auto sB = (__hip_bfloat16(*)[64])(smem + 16384);  // [128][64]

  const unsigned nwg = gridDim.x, gid = blockIdx.x;
  const unsigned q = nwg >> 3, r8 = nwg & 7, xc = gid & 7, jj = gid >> 3;
  const unsigned wg = (xc < r8 ? xc * (q + 1) : r8 * (q + 1) + (xc - r8) * q) + jj;
  const int m0 = (int)(wg % (unsigned)ntm) << 7;
  const int n0 = (int)(wg / (unsigned)ntm) << 7;

  const int tid = threadIdx.x;
  const int l = tid & 63, w = tid >> 6;
  const int wm = (w & 1) << 6, wn = (w >> 1) << 6;
  const int lr = l & 15;
  const int lk = (l >> 4) << 3;
  const int lrow = (w << 3) + (l >> 3);
  const int lcol = (l & 7) << 3;

  f32x4 acc[4][4];
  #pragma unroll
  for (int i = 0; i < 4; ++i)
    #pragma unroll
    for (int j = 0; j < 4; ++j) acc[i][j] = {0.f, 0.f, 0.f, 0.f};

  for (int k0 = 0; k0 < K; k0 += 64) {
    #pragma unroll
    for (int rr = 0; rr < 4; ++rr) {
      gl_lds16(A + (size_t)(m0 + (rr << 5) + lrow) * lda + k0 + lcol, &sA[(rr << 5) + (w << 3)][0]);
      gl_lds16(B + (size_t)(n0 + (rr << 5) + lrow) * ldb + k0 + lcol, &sB[(rr << 5) + (w << 3)][0]);
    }
    __syncthreads();
    #pragma unroll
    for (int kk = 0; kk < 64; kk += 32) {
      short8 aF[4], bF[4];
      #pragma unroll
      for (int ms = 0; ms < 4; ++ms) aF[ms] = *(const short8*)(&sA[wm + (ms << 4) + lr][kk + lk]);
      #pragma unroll
      for (int ns = 0; ns < 4; ++ns) bF[ns] = *(const short8*)(&sB[wn + (ns << 4) + lr][kk + lk]);
      #pragma unroll
      for (int ms = 0; ms < 4; ++ms)
        #pragma unroll
        for (int ns = 0; ns < 4; ++ns)
          acc[ms][ns] = __builtin_amdgcn_mfma_f32_16x16x32_bf16(aF[ms], bF[ns], acc[ms][ns], 0, 0, 0);
    }
    __syncthreads();
  }

  float* sg = (float*)smem + w * 1088;
  const int r2w = l >> 4;
  const int cw = l & 15;
  const int rbase = r2w << 2;
  #pragma unroll
  for (int ms = 0; ms < 4; ++ms) {
    #pragma unroll
    for (int ns = 0; ns < 4; ++ns)
      #pragma unroll
      for (int r = 0; r < 4; ++r) sg[(rbase + r) * 68 + (ns << 4) + lr] = acc[ms][ns][r];
    #pragma unroll
    for (int qq = 0; qq < 4; ++qq) {
      const int srow2 = (qq << 2) + r2w;
      float4 v = *(const float4*)&sg[srow2 * 68 + (cw << 2)];
      const int row = m0 + wm + (ms << 4) + srow2;
      const int col = n0 + wn + (cw << 2);
      if (bias1) {
        float4 b1 = *(const float4*)&bias1[col];
        v.x += b1.x; v.y += b1.y; v.z += b1.z; v.w += b1.w;
      }
      *(float4*)&C[(size_t)row * ldc + col] = v;
    }
  }
}

// ---------------- GRU core (v5 protocol, proven) + reg-hoisted bhh/tp; [t][b] UC dec_out + doneCnt ----------------
__device__ __forceinline__ void gru_core(
    const int slice, const int bg,
    const float* __restrict__ xp, const uint2* __restrict__ whhB,
    const float* __restrict__ bhh,
    ull* __restrict__ hTag, unsigned* __restrict__ decOutU,  // null or u32-packed bf16 [2048*512/2], row r2=t*32+bb
    unsigned* __restrict__ doneCnt,                          // null or [64]
    char* smem,
    const ull* __restrict__ thoughtTag,   // null or encoder hTag buf0 (thought w/ tag 64)
    const float* __restrict__ decWih,     // f32 [1536][1024] (only if thoughtTag)
    const float* __restrict__ dec_bih) {  // f32 [1536]       (only if thoughtTag)
  float* sH = (float*)smem;                 // 2048 f32 (8KB)
  float* sRed = (float*)(smem + 8192);      // 512*13 f32 (26.6KB)
  const int tid = threadIdx.x;
  const int i0 = slice << 5;
  const int il = tid & 31, kc = tid >> 5;   // 32 i x 16 k-chunks(32k each)
  const int kb0 = kc << 5;

  // ---- step-invariant weights -> 96 VGPRs ----
  float wrF[32], wzF[32], wnF[32];
  {
    const uint2* wp = whhB + i0 + il;
    #pragma unroll
    for (int k4 = 0; k4 < 8; ++k4) {
      #pragma unroll
      for (int j = 0; j < 4; ++j) {
        const int idx = (k4 << 2) + j;
        uint2 wv = wp[(size_t)(kb0 + idx) << 9];
        wrF[idx] = __uint_as_float(wv.x << 16);
        wzF[idx] = __uint_as_float(wv.x & 0xffff0000u);
        wnF[idx] = __uint_as_float(wv.y << 16);
      }
    }
  }

  // ---- tail invariants: bhh, tp (thought projection) ----
  float bh_r = 0.f, bh_z = 0.f, bh_n = 0.f;
  float tpr = 0.f, tpz = 0.f, tpn = 0.f;
  int gi = 0, bb = 0;
  if (tid < 128) {
    const int b = tid >> 5, i2 = tid & 31;
    gi = i0 + i2;
    bb = (bg << 2) + b;
    bh_r = bhh[gi]; bh_z = bhh[512 + gi]; bh_n = bhh[1024 + gi];
  }
  if (thoughtTag) {
    #pragma unroll
    for (int j = 0; j < 4; ++j) {
      ull v = __hip_atomic_load(thoughtTag + ((size_t)bg << 11) + (j << 9) + tid,
                                __ATOMIC_RELAXED, __HIP_MEMORY_SCOPE_AGENT);
      sH[(j << 9) + tid] = fmaxf(__uint_as_float((unsigned)v), 0.f);
    }
    __syncthreads();
    if (tid < 384) {
      const int b = tid / 96, j = tid % 96;
      const int g = j >> 5, i2 = j & 31;
      const int row = g * 512 + i0 + i2;
      const float4* w4 = (const float4*)(decWih + (size_t)row * 1024 + 512);
      const float* th = &sH[b << 9];
      float s = dec_bih[row];
      #pragma unroll 4
      for (int k = 0; k < 128; ++k) {
        float4 w = w4[k];
        float4 t4 = *(const float4*)&th[k << 2];
        s += w.x * t4.x + w.y * t4.y + w.z * t4.z + w.w * t4.w;
      }
      sRed[tid] = s;
    }
    __syncthreads();
    if (tid < 128) {
      const int b = tid >> 5, i2 = tid & 31;
      tpr = sRed[b * 96 + i2];
      tpz = sRed[b * 96 + 32 + i2];
      tpn = sRed[b * 96 + 64 + i2];
    }
    __syncthreads();
  }

  #pragma unroll 1
  for (int t = 0; t < Tt; ++t) {
    // poll + load h(t) (tag word = {step<<32 | f32}, buffer = t parity)
    {
      const ull* hb = hTag + ((size_t)(t & 1) << 14) + ((size_t)bg << 11);
      #pragma unroll
      for (int j = 0; j < 4; ++j) {
        const ull* p = hb + (j << 9) + tid;
        ull v = __hip_atomic_load(p, __ATOMIC_RELAXED, __HIP_MEMORY_SCOPE_AGENT);
        while ((unsigned)(v >> 32) != (unsigned)t) {
          __builtin_amdgcn_s_sleep(1);
          v = __hip_atomic_load(p, __ATOMIC_RELAXED, __HIP_MEMORY_SCOPE_AGENT);
        }
        sH[(j << 9) + tid] = __uint_as_float((unsigned)v);
      }
    }
    __syncthreads();   // B0

    float a[12];
    #pragma unroll
    for (int v = 0; v < 12; ++v) a[v] = 0.f;
    #pragma unroll
    for (int k4 = 0; k4 < 8; ++k4) {
      const int kb = kb0 + (k4 << 2);
      float4 hv0 = *(const float4*)&sH[kb];
      float4 hv1 = *(const float4*)&sH[512 + kb];
      float4 hv2 = *(const float4*)&sH[1024 + kb];
      float4 hv3 = *(const float4*)&sH[1536 + kb];
      const float* h0p = (const float*)&hv0;
      const float* h1p = (const float*)&hv1;
      const float* h2p = (const float*)&hv2;
      const float* h3p = (const float*)&hv3;
      #pragma unroll
      for (int j = 0; j < 4; ++j) {
        const int idx = (k4 << 2) + j;
        const float wr = wrF[idx], wz = wzF[idx], wn = wnF[idx];
        a[0]  = fmaf(wr, h0p[j], a[0]);  a[1]  = fmaf(wz, h0p[j], a[1]);  a[2]  = fmaf(wn, h0p[j], a[2]);
        a[3]  = fmaf(wr, h1p[j], a[3]);  a[4]  = fmaf(wz, h1p[j], a[4]);  a[5]  = fmaf(wn, h1p[j], a[5]);
        a[6]  = fmaf(wr, h2p[j], a[6]);  a[7]  = fmaf(wz, h2p[j], a[7]);  a[8]  = fmaf(wn, h2p[j], a[8]);
        a[9]  = fmaf(wr, h3p[j], a[9]);  a[10] = fmaf(wz, h3p[j], a[10]); a[11] = fmaf(wn, h3p[j], a[11]);
      }
    }
    {
      float* red = &sRed[tid * 13];
      #pragma unroll
      for (int v = 0; v < 12; ++v) red[v] = a[v];
    }
    __syncthreads();   // B1

    if (tid < 128) {
      const int b = tid >> 5, i2 = tid & 31;
      float s0 = 0.f, s1 = 0.f, s2 = 0.f;
      #pragma unroll
      for (int kc2 = 0; kc2 < 16; ++kc2) {
        const float* rp = &sRed[(kc2 * 32 + i2) * 13 + b * 3];
        s0 += rp[0]; s1 += rp[1]; s2 += rp[2];
      }
      const float hr = s0 + bh_r;
      const float hz = s1 + bh_z;
      const float hn = s2 + bh_n;
      const size_t m = (size_t)bb * Tt + t;
      const float xr = xp[m * G3 + gi] + tpr;
      const float xz = xp[m * G3 + 512 + gi] + tpz;
      const float xn = xp[m * G3 + 1024 + gi] + tpn;
      const float rg = 1.f / (1.f + __expf(-(xr + hr)));
      const float zg = 1.f / (1.f + __expf(-(xz + hz)));
      const float ng = tanhf(xn + rg * hn);
      const float hnew = (1.f - zg) * ng + zg * sH[(b << 9) + gi];
      ull* dst = hTag + ((size_t)((t + 1) & 1) << 14) + ((size_t)bb << 9) + gi;
      __hip_atomic_store(dst, ((ull)(unsigned)(t + 1) << 32) | (ull)__float_as_uint(hnew),
                         __ATOMIC_RELAXED, __HIP_MEMORY_SCOPE_AGENT);
      if (decOutU) {
        // [t][b] layout, UC paired-u32 store: row r2=t*32+bb, col gi; even lane packs (gi, gi+1)
        unsigned bbits = bf16bits(hnew);
        unsigned pbits = __shfl_down(bbits, 1);
        if (!(tid & 1)) {
          const int r2 = (t << 5) + bb;
          __hip_atomic_store(decOutU + (((r2 << 9) + gi) >> 1), (pbits << 16) | bbits,
                             __ATOMIC_RELAXED, __HIP_MEMORY_SCOPE_AGENT);
        }
      }
    }
    __syncthreads();   // B2: drains UC stores (vmcnt 0) before flag
    if (doneCnt && tid == 0) {
      __hip_atomic_fetch_add(doneCnt + t, 1u, __ATOMIC_RELAXED, __HIP_MEMORY_SCOPE_AGENT);
    }
  }
}

// ---------------- 128x128 tile GEMM core (cached A+B, f32 out) for enc_fused dec_xp ----------------
__device__ __forceinline__ void gemm_tile_core(
    const int tid, const int m0, const int n0,
    const __hip_bfloat16* __restrict__ A, const __hip_bfloat16* __restrict__ B,
    float* __restrict__ C, int lda, int ldb, int ldc, int K, char* smem) {
  auto sA = (__hip_bfloat16(*)[64])smem;
  auto sB = (__hip_bfloat16(*)[64])(smem + 16384);
  const int l = tid & 63, w = tid >> 6;
  const int wm = (w & 1) << 6, wn = (w >> 1) << 6;
  const int lr = l & 15;
  const int lk = (l >> 4) << 3;
  const int lrow = (w << 3) + (l >> 3);
  const int lcol = (l & 7) << 3;

  f32x4 acc[4][4];
  #pragma unroll
  for (int i = 0; i < 4; ++i)
    #pragma unroll
    for (int j = 0; j < 4; ++j) acc[i][j] = {0.f, 0.f, 0.f, 0.f};

  for (int k0 = 0; k0 < K; k0 += 64) {
    #pragma unroll
    for (int rr = 0; rr < 4; ++rr) {
      gl_lds16(A + (size_t)(m0 + (rr << 5) + lrow) * lda + k0 + lcol, &sA[(rr << 5) + (w << 3)][0]);
      gl_lds16(B + (size_t)(n0 + (rr << 5) + lrow) * ldb + k0 + lcol, &sB[(rr << 5) + (w << 3)][0]);
    }
    __syncthreads();
    #pragma unroll
    for (int kk = 0; kk < 64; kk += 32) {
      short8 aF[4], bF[4];
      #pragma unroll
      for (int ms = 0; ms < 4; ++ms) aF[ms] = *(const short8*)(&sA[wm + (ms << 4) + lr][kk + lk]);
      #pragma unroll
      for (int ns = 0; ns < 4; ++ns) bF[ns] = *(const short8*)(&sB[wn + (ns << 4) + lr][kk + lk]);
      #pragma unroll
      for (int ms = 0; ms < 4; ++ms)
        #pragma unroll
        for (int ns = 0; ns < 4; ++ns)
          acc[ms][ns] = __builtin_amdgcn_mfma_f32_16x16x32_bf16(aF[ms], bF[ns], acc[ms][ns], 0, 0, 0);
    }
    __syncthreads();
  }

  float* sg = (float*)smem + w * 1088;
  const int r2w = l >> 4;
  const int cw = l & 15;
  const int rbase = r2w << 2;
  #pragma unroll
  for (int ms = 0; ms < 4; ++ms) {
    #pragma unroll
    for (int ns = 0; ns < 4; ++ns)
      #pragma unroll
      for (int r = 0; r < 4; ++r) sg[(rbase + r) * 68 + (ns << 4) + lr] = acc[ms][ns][r];
    #pragma unroll
    for (int qq = 0; qq < 4; ++qq) {
      const int srow2 = (qq << 2) + r2w;
      float4 v = *(const float4*)&sg[srow2 * 68 + (cw << 2)];
      *(float4*)&C[(size_t)(m0 + wm + (ms << 4) + srow2) * ldc + n0 + wn + (cw << 2)] = v;
    }
  }
}

// ---------------- logits tile core: A via CACHED global_load_lds ----------------
// Coherence: decOutU lines are write-once (UC, to LLC) and first READ strictly after the
// doneCnt gate -> cached read cannot observe a pre-write copy (validated round 15).
// Output rows remapped r2->m=(bb<<6)+t in epilogue; emits partials + bf16/f32 logits.
__device__ __forceinline__ void gemm_logits_core(
    const int tid, const int m0, const int n0,
    const __hip_bfloat16* __restrict__ Abf,  // decOut bf16, [t][b] rows, lda=512
    const __hip_bfloat16* __restrict__ B,    // outW_bf [32000][512]
    const float* __restrict__ out_b,
    float* __restrict__ outF, __hip_bfloat16* __restrict__ outBf,
    float2* __restrict__ partials, const int bfOut, char* smem) {
  auto sA = (__hip_bfloat16(*)[64])smem;
  auto sB = (__hip_bfloat16(*)[64])(smem + 16384);
  const int l = tid & 63, w = tid >> 6;
  const int wm = (w & 1) << 6, wn = (w >> 1) << 6;
  const int lr = l & 15;
  const int lk = (l >> 4) << 3;
  const int lrow = (w << 3) + (l >> 3);
  const int lcol = (l & 7) << 3;

  f32x4 acc[4][4];
  #pragma unroll
  for (int i = 0; i < 4; ++i)
    #pragma unroll
    for (int j = 0; j < 4; ++j) acc[i][j] = {0.f, 0.f, 0.f, 0.f};

  for (int k0 = 0; k0 < 512; k0 += 64) {
    #pragma unroll
    for (int rr = 0; rr < 4; ++rr) {
      gl_lds16(Abf + (size_t)(m0 + (rr << 5) + lrow) * 512 + k0 + lcol, &sA[(rr << 5) + (w << 3)][0]);
      gl_lds16(B + (size_t)(n0 + (rr << 5) + lrow) * 512 + k0 + lcol, &sB[(rr << 5) + (w << 3)][0]);
    }
    __syncthreads();
    #pragma unroll
    for (int kk = 0; kk < 64; kk += 32) {
      short8 aF[4], bF[4];
      #pragma unroll
      for (int ms = 0; ms < 4; ++ms) aF[ms] = *(const short8*)(&sA[wm + (ms << 4) + lr][kk + lk]);
      #pragma unroll
      for (int ns = 0; ns < 4; ++ns) bF[ns] = *(const short8*)(&sB[wn + (ns << 4) + lr][kk + lk]);
      #pragma unroll
      for (int ms = 0; ms < 4; ++ms)
        #pragma unroll
        for (int ns = 0; ns < 4; ++ns)
          acc[ms][ns] = __builtin_amdgcn_mfma_f32_16x16x32_bf16(aF[ms], bF[ns], acc[ms][ns], 0, 0, 0);
    }
    __syncthreads();
  }

  float* sg = (float*)smem + w * 1088;
  const int r2w = l >> 4;
  const int cw = l & 15;
  const int rbase = r2w << 2;
  #pragma unroll
  for (int ms = 0; ms < 4; ++ms) {
    #pragma unroll
    for (int ns = 0; ns < 4; ++ns)
      #pragma unroll
      for (int r = 0; r < 4; ++r) sg[(rbase + r) * 68 + (ns << 4) + lr] = acc[ms][ns][r];
    #pragma unroll
    for (int qq = 0; qq < 4; ++qq) {
      const int srow2 = (qq << 2) + r2w;
      float4 v = *(const float4*)&sg[srow2 * 68 + (cw << 2)];
      const int r2a = m0 + wm + (ms << 4) + srow2;          // [t][b] row
      const int mrow = ((r2a & 31) << 6) + (r2a >> 5);      // final row b*64+t
      const int col = n0 + wn + (cw << 2);
      float4 b1 = *(const float4*)&out_b[col];
      v.x += b1.x; v.y += b1.y; v.z += b1.z; v.w += b1.w;
      float m4 = fmaxf(fmaxf(v.x, v.y), fmaxf(v.z, v.w));
      #pragma unroll
      for (int hop = 1; hop < 16; hop <<= 1) m4 = fmaxf(m4, __shfl_xor(m4, hop));
      float e = __expf(v.x - m4) + __expf(v.y - m4) + __expf(v.z - m4) + __expf(v.w - m4);
      #pragma unroll
      for (int hop = 1; hop < 16; hop <<= 1) e += __shfl_xor(e, hop);
      if (cw == 0) partials[(size_t)mrow * 500 + ((n0 >> 6) + (wn >> 6))] = make_float2(m4, e);
      if (bfOut) {
        union { __hip_bfloat16 h[4]; uint2 u; } o;
        o.h[0] = __float2bfloat16(v.x);
        o.h[1] = __float2bfloat16(v.y);
        o.h[2] = __float2bfloat16(v.z);
        o.h[3] = __float2bfloat16(v.w);
        *(uint2*)&outBf[(size_t)mrow * Vv + col] = o.u;
      } else {
        *(float4*)&outF[(size_t)mrow * Vv + col] = v;
      }
    }
  }
}

// ---------------- FUSED: encoder GRU (XCDs 0-3) || dec_xp GEMM + outW cvt (XCDs 4-7) ----------------
// Round-16: XCD role partitioning. blk -> XCD is round-robin (blk&7, heuristic, perf-only):
// GRU blocks get XCDs 0-3 (private L2s for xp/hTag latency path); GEMM/cvt traffic
// confined to XCDs 4-7. Bijective id remap: g/w = (blk>>3)*4 + (blk&3).
__global__ __launch_bounds__(512, 1) void enc_fused_k(
    const float* __restrict__ enc_xp, const uint2* __restrict__ whhB_e,
    const float* __restrict__ enc_bhh, ull* __restrict__ hTag_e,
    const __hip_bfloat16* __restrict__ decX_bf, const __hip_bfloat16* __restrict__ decWih_bf,
    float* __restrict__ dec_xp,
    const float* __restrict__ out_W, __hip_bfloat16* __restrict__ outW_bf) {
  __shared__ __align__(16) char smem[65536];
  const int blk = blockIdx.x;
  const int xcd = blk & 7;
  if (xcd < 4) {
    const int g = ((blk >> 3) << 2) + xcd;              // 0..127
    gru_core(g & 15, g >> 4, enc_xp, whhB_e, enc_bhh, hTag_e, nullptr, nullptr, smem,
             nullptr, nullptr, nullptr);
  } else {
    const int wkr = ((blk >> 3) << 2) + (xcd - 4);      // 0..127
    if (wkr < 96) {
      const int half = threadIdx.x >> 8;
      const int tile = (wkr << 1) + half;               // 0..191
      const int m0 = (tile & 15) << 7;
      const int n0 = (tile >> 4) << 7;
      gemm_tile_core(threadIdx.x & 255, m0, n0, decX_bf, decWih_bf, dec_xp,
                     512, 1024, G3, 512, smem + (half << 15));
    } else {
      const int n4 = Vv * Hh / 4;
      for (int i = ((wkr - 96) << 9) + threadIdx.x; i < n4; i += 32 * 512) {
        float4 v = ((const float4*)out_W)[i];
        union { __hip_bfloat16 h[4]; uint2 u; } o;
        o.h[0] = __float2bfloat16(v.x);
        o.h[1] = __float2bfloat16(v.y);
        o.h[2] = __float2bfloat16(v.z);
        o.h[3] = __float2bfloat16(v.w);
        ((uint2*)outW_bf)[i] = o.u;
      }
    }
  }
}

// ---------------- FUSED: decoder GRU (XCDs 0-3) || logits GEMM workers (XCDs 4-7) ----------------
// Workers sweep tiles in ascending-t order, polling doneCnt[t_hi]==128 (UC). Acyclic waits.
// Grid 256 blocks (co-resident). XCD partition keeps worker HBM/L2 streams off the GRU's
// latency-critical L2s.
__global__ __launch_bounds__(512, 1) void dec_fused_k(
    const float* __restrict__ dec_xp, const uint2* __restrict__ whhB_d,
    const float* __restrict__ dec_bhh,
    const ull* __restrict__ thoughtTag, const float* __restrict__ dec_Wih,
    const float* __restrict__ dec_bih,
    ull* __restrict__ hTag_d, unsigned* __restrict__ decOutU, unsigned* __restrict__ doneCnt,
    const __hip_bfloat16* __restrict__ outW_bf, const float* __restrict__ out_b,
    float* __restrict__ outF, __hip_bfloat16* __restrict__ logitsBf,
    float2* __restrict__ partials, int bfOut) {
  __shared__ __align__(16) char smem[65536];
  const int blk = blockIdx.x;
  const int xcd = blk & 7;
  if (xcd < 4) {
    const int g = ((blk >> 3) << 2) + xcd;              // 0..127
    gru_core(g & 15, g >> 4, dec_xp, whhB_d, dec_bhh, hTag_d, decOutU, doneCnt, smem,
             thoughtTag, dec_Wih, dec_bih);
  } else {
    const int b = ((blk >> 3) << 2) + (xcd - 4);        // 0..127
    const int tid = threadIdx.x;
    #pragma unroll 1
    for (int j = 0; j < 16; ++j) {
      const int p = j * 128 + b;           // pair index, covers tiles {2p, 2p+1}
      if (p >= 2000) break;                // 4000 tiles = 2000 pairs
      const int mT = (2 * p + 1) / 250;    // max mTile of the pair (tiles are m-major)
      const int thi = 4 * mT + 3;          // last timestep this pair's rows need
      if (tid == 0) {
        while (__hip_atomic_load(doneCnt + thi, __ATOMIC_RELAXED, __HIP_MEMORY_SCOPE_AGENT) < 128u)
          __builtin_amdgcn_s_sleep(4);
      }
      __syncthreads();
      const int half = tid >> 8;
      const int tile = 2 * p + half;
      gemm_logits_core(tid & 255, (tile / 250) << 7, (tile % 250) << 7,
                       (const __hip_bfloat16*)decOutU, outW_bf, out_b, outF, logitsBf,
                       partials, bfOut, smem + (half << 15));
    }
  }
}

// ---------------- final log-softmax (f32 logits in place) ----------------
__global__ __launch_bounds__(256) void lsm_final_k(float* __restrict__ X,
                                                   const float2* __restrict__ P) {
  const int row = blockIdx.x;
  const int tid = threadIdx.x;
  float m = -3.4e38f, s = 0.f;
  for (int j = tid; j < 500; j += 256) {
    float2 p = P[(size_t)row * 500 + j];
    if (p.x > m) { s = s * __expf(m - p.x) + p.y; m = p.x; }
    else         { s += p.y * __expf(p.x - m); }
  }
  #pragma unroll
  for (int off2 = 32; off2 > 0; off2 >>= 1) {
    float mo = __shfl_down(m, off2);
    float so = __shfl_down(s, off2);
    float M = fmaxf(m, mo);
    s = s * __expf(m - M) + so * __expf(mo - M);
    m = M;
  }
  __shared__ float sm[4], ss[4];
  if ((tid & 63) == 0) { sm[tid >> 6] = m; ss[tid >> 6] = s; }
  __syncthreads();
  const float M4 = fmaxf(fmaxf(sm[0], sm[1]), fmaxf(sm[2], sm[3]));
  const float S = ss[0] * __expf(sm[0] - M4) + ss[1] * __expf(sm[1] - M4) +
                  ss[2] * __expf(sm[2] - M4) + ss[3] * __expf(sm[3] - M4);
  const float c = M4 + __logf(S);
  float4* p4 = (float4*)(X + (size_t)row * Vv);
  for (int j = tid; j < Vv / 4; j += 256) {
    float4 v = p4[j];
    v.x -= c; v.y -= c; v.z -= c; v.w -= c;
    p4[j] = v;
  }
}

// ---------------- final log-softmax (bf16 logits -> f32 d_out) ----------------
__global__ __launch_bounds__(256) void lsm_final2_k(float* __restrict__ X,
                                                    const __hip_bfloat16* __restrict__ L,
                                                    const float2* __restrict__ P) {
  const int row = blockIdx.x;
  const int tid = threadIdx.x;
  float m = -3.4e38f, s = 0.f;
  for (int j = tid; j < 500; j += 256) {
    float2 p = P[(size_t)row * 500 + j];
    if (p.x > m) { s = s * __expf(m - p.x) + p.y; m = p.x; }
    else         { s += p.y * __expf(p.x - m); }
  }
  #pragma unroll
  for (int off2 = 32; off2 > 0; off2 >>= 1) {
    float mo = __shfl_down(m, off2);
    float so = __shfl_down(s, off2);
    float M = fmaxf(m, mo);
    s = s * __expf(m - M) + so * __expf(mo - M);
    m = M;
  }
  __shared__ float sm[4], ss[4];
  if ((tid & 63) == 0) { sm[tid >> 6] = m; ss[tid >> 6] = s; }
  __syncthreads();
  const float M4 = fmaxf(fmaxf(sm[0], sm[1]), fmaxf(sm[2], sm[3]));
  const float S = ss[0] * __expf(sm[0] - M4) + ss[1] * __expf(sm[1] - M4) +
                  ss[2] * __expf(sm[2] - M4) + ss[3] * __expf(sm[3] - M4);
  const float c = M4 + __logf(S);
  const short8* p8 = (const short8*)(L + (size_t)row * Vv);
  float4* o4 = (float4*)(X + (size_t)row * Vv);
  for (int j = tid; j < Vv / 8; j += 256) {
    short8 sv = p8[j];
    float4 a, b;
    a.x = __uint_as_float(((unsigned)(unsigned short)sv[0]) << 16) - c;
    a.y = __uint_as_float(((unsigned)(unsigned short)sv[1]) << 16) - c;
    a.z = __uint_as_float(((unsigned)(unsigned short)sv[2]) << 16) - c;
    a.w = __uint_as_float(((unsigned)(unsigned short)sv[3]) << 16) - c;
    b.x = __uint_as_float(((unsigned)(unsigned short)sv[4]) << 16) - c;
    b.y = __uint_as_float(((unsigned)(unsigned short)sv[5]) << 16) - c;
    b.z = __uint_as_float(((unsigned)(unsigned short)sv[6]) << 16) - c;
    b.w = __uint_as_float(((unsigned)(unsigned short)sv[7]) << 16) - c;
    o4[(j << 1)] = a;
    o4[(j << 1) + 1] = b;
  }
}

}  // namespace

extern "C" void kernel_launch(void* const* d_in, const int* in_sizes, int n_in,
                              void* d_out, int out_size, void* d_ws, size_t ws_size,
                              hipStream_t stream) {
  (void)in_sizes; (void)n_in; (void)out_size;
  const int*   in_seq  = (const int*)d_in[0];
  const int*   tgt_seq = (const int*)d_in[1];
  const float* enc_emb = (const float*)d_in[2];
  const float* enc_Wih = (const float*)d_in[3];
  const float* enc_Whh = (const float*)d_in[4];
  const float* enc_bih = (const float*)d_in[5];
  const float* enc_bhh = (const float*)d_in[6];
  const float* dec_emb = (const float*)d_in[7];
  const float* dec_Wih = (const float*)d_in[8];
  const float* dec_Whh = (const float*)d_in[9];
  const float* dec_bih = (const float*)d_in[10];
  const float* dec_bhh = (const float*)d_in[11];
  const float* out_W   = (const float*)d_in[12];
  const float* out_b   = (const float*)d_in[13];
  float* out = (float*)d_out;

  char* ws = (char*)d_ws;
  size_t off = 0;
  auto alloc = [&](size_t bytes) -> void* {
    void* p = (void*)(ws + off);
    off += (bytes + 255) & ~(size_t)255;
    return p;
  };
  uint2* whhB_e            = (uint2*)alloc((size_t)512 * 512 * 8);
  uint2* whhB_d            = (uint2*)alloc((size_t)512 * 512 * 8);
  __hip_bfloat16* encWih_bf = (__hip_bfloat16*)alloc((size_t)1536 * 512 * 2);
  __hip_bfloat16* decWih_bf = (__hip_bfloat16*)alloc((size_t)1536 * 1024 * 2);
  __hip_bfloat16* outW_bf   = (__hip_bfloat16*)alloc((size_t)32000 * 512 * 2);
  __hip_bfloat16* encX_bf   = (__hip_bfloat16*)alloc((size_t)2048 * 512 * 2);
  __hip_bfloat16* decX_bf   = (__hip_bfloat16*)alloc((size_t)2048 * 512 * 2);
  float* enc_xp            = (float*)alloc((size_t)2048 * 1536 * 4);
  float* dec_xp            = (float*)alloc((size_t)2048 * 1536 * 4);
  ull* hTag_e              = (ull*)alloc((size_t)2 * 32 * 512 * 8);   // 256KB
  ull* hTag_d              = (ull*)alloc((size_t)2 * 32 * 512 * 8);   // 256KB (contiguous after hTag_e)
  unsigned* doneCnt        = (unsigned*)alloc((size_t)64 * 4);        // contiguous after hTag_d
  unsigned* decOutU        = (unsigned*)alloc((size_t)2048 * 512 * 2);// 2MB packed bf16 [t][b]
  float2* partials         = (float2*)alloc((size_t)2048 * 500 * 8);  // 8.2MB
  __hip_bfloat16* logitsBf  = (__hip_bfloat16*)alloc((size_t)2048 * Vv * 2);  // 131MB (optional)
  const bool bfLogits = (off <= ws_size);

  // --- merged preprocessing: cvt x2 | pack x2 | zero hTag_e+hTag_d+doneCnt ---
  prep_k<<<2689, 256, 0, stream>>>(enc_Wih, encWih_bf, dec_Wih, decWih_bf,
                                   enc_Whh, whhB_e, dec_Whh, whhB_d, (uint4*)hTag_e);

  // --- embeddings ---
  embed_k<<<2048, 128, 0, stream>>>(in_seq, enc_emb, encX_bf, 0);
  embed_k<<<2048, 128, 0, stream>>>(tgt_seq, dec_emb, decX_bf, 1);

  // --- encoder xp = enc_x @ Wih^T + bih : [2048,1536] ---
  gemm_bf16_k<<<192, 256, 0, stream>>>(encX_bf, encWih_bf, enc_xp,
                                       512, 512, G3, 512, enc_bih, 16);

  // --- FUSED: encoder GRU (XCDs 0-3) || dec_xp GEMM + outW cvt (XCDs 4-7) ---
  enc_fused_k<<<256, 512, 0, stream>>>(enc_xp, whhB_e, enc_bhh, hTag_e,
                                       decX_bf, decWih_bf, dec_xp, out_W, outW_bf);
  // thought = h(64) w/ tag 64 lives in hTag_e buffer 0

  // --- FUSED: decoder GRU (XCDs 0-3) || logits GEMM workers (XCDs 4-7) ---
  dec_fused_k<<<256, 512, 0, stream>>>(dec_xp, whhB_d, dec_bhh,
                                       hTag_e, dec_Wih, dec_bih,
                                       hTag_d, decOutU, doneCnt,
                                       outW_bf, out_b,
                                       out, logitsBf, partials, bfLogits ? 1 : 0);

  // --- final log-softmax ---
  if (bfLogits) {
    lsm_final2_k<<<2048, 256, 0, stream>>>(out, logitsBf, partials);
  } else {
    lsm_final_k<<<2048, 256, 0, stream>>>(out, partials);
  }
}

// Round 17
// 761.869 us; speedup vs baseline: 1.1648x; 1.0546x over previous
//
#include <hip/hip_runtime.h>
#include <hip/hip_bf16.h>
#include <cstdint>
#include <cstddef>

namespace {

constexpr int Hh = 512;
constexpr int G3 = 1536;   // 3*H
constexpr int Bb = 32;
constexpr int Tt = 64;
constexpr int Vv = 32000;

typedef __attribute__((ext_vector_type(8))) short short8;
typedef __attribute__((ext_vector_type(4))) float f32x4;
typedef unsigned long long ull;

__device__ __forceinline__ unsigned bf16bits(float f) {
  union { __hip_bfloat16 h; unsigned short u; } c;
  c.h = __float2bfloat16(f);
  return (unsigned)c.u;
}

// async global->LDS, 16B per lane; LDS dest = wave-uniform base + lane*16
__device__ __forceinline__ void gl_lds16(const void* g, void* l) {
  __builtin_amdgcn_global_load_lds(
      (const __attribute__((address_space(1))) unsigned int*)g,
      (__attribute__((address_space(3))) unsigned int*)l, 16, 0, 0);
}

// ---------------- merged preprocessing: cvt x2 | pack x2 | zero hTag_e+hTag_d+doneCnt+workCtr ----------------
__device__ __forceinline__ void cvt_range(const float* __restrict__ src,
                                          __hip_bfloat16* __restrict__ dst, int i, int n4) {
  if (i >= n4) return;
  float4 v = ((const float4*)src)[i];
  union { __hip_bfloat16 h[4]; uint2 u; } o;
  o.h[0] = __float2bfloat16(v.x);
  o.h[1] = __float2bfloat16(v.y);
  o.h[2] = __float2bfloat16(v.z);
  o.h[3] = __float2bfloat16(v.w);
  ((uint2*)dst)[i] = o.u;
}

__device__ __forceinline__ void pack_whh_core(const float* __restrict__ Whh,
                                              uint2* __restrict__ P, int k0, int i0) {
  __shared__ float tw[3][32][65];
  const int t = threadIdx.x;               // 256
  const int kk = t & 63, r4 = t >> 6;
  for (int ri = r4; ri < 96; ri += 4) {
    const int g = ri >> 5, ii = ri & 31;
    tw[g][ii][kk] = Whh[(size_t)(g * 512 + i0 + ii) * 512 + k0 + kk];
  }
  __syncthreads();
  const int ii = t & 31, kq = t >> 5;
  for (int k2 = kq; k2 < 64; k2 += 8) {
    unsigned rb = bf16bits(tw[0][ii][k2]);
    unsigned zb = bf16bits(tw[1][ii][k2]);
    unsigned nb = bf16bits(tw[2][ii][k2]);
    P[(size_t)(k0 + k2) * 512 + i0 + ii] = make_uint2((zb << 16) | rb, nb);
  }
}

__global__ __launch_bounds__(256) void prep_k(
    const float* __restrict__ enc_Wih, __hip_bfloat16* __restrict__ encWih_bf,
    const float* __restrict__ dec_Wih, __hip_bfloat16* __restrict__ decWih_bf,
    const float* __restrict__ enc_Whh, uint2* __restrict__ whhB_e,
    const float* __restrict__ dec_Whh, uint2* __restrict__ whhB_d,
    uint4* __restrict__ zeroBase) {
  const int blk = blockIdx.x;
  if (blk < 768) {
    cvt_range(enc_Wih, encWih_bf, blk * 256 + threadIdx.x, 1536 * 512 / 4);
  } else if (blk < 2304) {
    cvt_range(dec_Wih, decWih_bf, (blk - 768) * 256 + threadIdx.x, 1536 * 1024 / 4);
  } else if (blk < 2432) {
    const int b = blk - 2304;
    pack_whh_core(enc_Whh, whhB_e, (b & 7) * 64, (b >> 3) * 32);
  } else if (blk < 2560) {
    const int b = blk - 2432;
    pack_whh_core(dec_Whh, whhB_d, (b & 7) * 64, (b >> 3) * 32);
  } else {
    // zero hTag_e + hTag_d + doneCnt + workCtr (contiguous): 131200 u32 = 32800 uint4
    const int i = (blk - 2560) * 256 + threadIdx.x;
    if (i < 32800) zeroBase[i] = make_uint4(0u, 0u, 0u, 0u);
  }
}

// ---------------- embedding gather (optionally relu) -> bf16 [2048][512] ----------------
__global__ void embed_k(const int* __restrict__ idx, const float* __restrict__ emb,
                        __hip_bfloat16* __restrict__ outp, int do_relu) {
  int row = blockIdx.x;            // 0..2047 (= b*64+t)
  int r = idx[row];
  float4 v = ((const float4*)(emb + (size_t)r * Hh))[threadIdx.x];  // 128 thr * 4
  if (do_relu) {
    v.x = fmaxf(v.x, 0.f); v.y = fmaxf(v.y, 0.f);
    v.z = fmaxf(v.z, 0.f); v.w = fmaxf(v.w, 0.f);
  }
  union { __hip_bfloat16 h[4]; uint2 u; } o;
  o.h[0] = __float2bfloat16(v.x);
  o.h[1] = __float2bfloat16(v.y);
  o.h[2] = __float2bfloat16(v.z);
  o.h[3] = __float2bfloat16(v.w);
  ((uint2*)(outp + (size_t)row * Hh))[threadIdx.x] = o.u;
}

// ---------------- bf16 MFMA GEMM (standalone, f32 out + bias): used for enc_xp only ----------------
__global__ __launch_bounds__(256) void gemm_bf16_k(
    const __hip_bfloat16* __restrict__ A,
    const __hip_bfloat16* __restrict__ B,
    float* __restrict__ C,
    int lda, int ldb, int ldc, int K,
    const float* __restrict__ bias1,
    int ntm) {
  __shared__ __align__(16) char smem[32768];
  auto sA = (__hip_bfloat16(*)[64])smem;            // [128][64]
  auto sB = (__hip_bfloat16(*)[64])(smem + 16384);  // [128][64]

  const unsigned nwg = gridDim.x, gid = blockIdx.x;
  const unsigned q = nwg >> 3, r8 = nwg & 7, xc = gid & 7, jj = gid >> 3;
  const unsigned wg = (xc < r8 ? xc * (q + 1) : r8 * (q + 1) + (xc - r8) * q) + jj;
  const int m0 = (int)(wg % (unsigned)ntm) << 7;
  const int n0 = (int)(wg / (unsigned)ntm) << 7;

  const int tid = threadIdx.x;
  const int l = tid & 63, w = tid >> 6;
  const int wm = (w & 1) << 6, wn = (w >> 1) << 6;
  const int lr = l & 15;
  const int lk = (l >> 4) << 3;
  const int lrow = (w << 3) + (l >> 3);
  const int lcol = (l & 7) << 3;

  f32x4 acc[4][4];
  #pragma unroll
  for (int i = 0; i < 4; ++i)
    #pragma unroll
    for (int j = 0; j < 4; ++j) acc[i][j] = {0.f, 0.f, 0.f, 0.f};

  for (int k0 = 0; k0 < K; k0 += 64) {
    #pragma unroll
    for (int rr = 0; rr < 4; ++rr) {
      gl_lds16(A + (size_t)(m0 + (rr << 5) + lrow) * lda + k0 + lcol, &sA[(rr << 5) + (w << 3)][0]);
      gl_lds16(B + (size_t)(n0 + (rr << 5) + lrow) * ldb + k0 + lcol, &sB[(rr << 5) + (w << 3)][0]);
    }
    __syncthreads();
    #pragma unroll
    for (int kk = 0; kk < 64; kk += 32) {
      short8 aF[4], bF[4];
      #pragma unroll
      for (int ms = 0; ms < 4; ++ms) aF[ms] = *(const short8*)(&sA[wm + (ms << 4) + lr][kk + lk]);
      #pragma unroll
      for (int ns = 0; ns < 4; ++ns) bF[ns] = *(const short8*)(&sB[wn + (ns << 4) + lr][kk + lk]);
      #pragma unroll
      for (int ms = 0; ms < 4; ++ms)
        #pragma unroll
        for (int ns = 0; ns < 4; ++ns)
          acc[ms][ns] = __builtin_amdgcn_mfma_f32_16x16x32_bf16(aF[ms], bF[ns], acc[ms][ns], 0, 0, 0);
    }
    __syncthreads();
  }

  float* sg = (float*)smem + w * 1088;
  const int r2w = l >> 4;
  const int cw = l & 15;
  const int rbase = r2w << 2;
  #pragma unroll
  for (int ms = 0; ms < 4; ++ms) {
    #pragma unroll
    for (int ns = 0; ns < 4; ++ns)
      #pragma unroll
      for (int r = 0; r < 4; ++r) sg[(rbase + r) * 68 + (ns << 4) + lr] = acc[ms][ns][r];
    #pragma unroll
    for (int qq = 0; qq < 4; ++qq) {
      const int srow2 = (qq << 2) + r2w;
      float4 v = *(const float4*)&sg[srow2 * 68 + (cw << 2)];
      const int row = m0 + wm + (ms << 4) + srow2;
      const int col = n0 + wn + (cw << 2);
      if (bias1) {
        float4 b1 = *(const float4*)&bias1[col];
        v.x += b1.x; v.y += b1.y; v.z += b1.z; v.w += b1.w;
      }
      *(float4*)&C[(size_t)row * ldc + col] = v;
    }
  }
}

// ---------------- GRU core (v5 protocol, proven) + reg-hoisted bhh/tp; [t][b] UC dec_out + doneCnt ----------------
__device__ __forceinline__ void gru_core(
    const int slice, const int bg,
    const float* __restrict__ xp, const uint2* __restrict__ whhB,
    const float* __restrict__ bhh,
    ull* __restrict__ hTag, unsigned* __restrict__ decOutU,  // null or u32-packed bf16 [2048*512/2], row r2=t*32+bb
    unsigned* __restrict__ doneCnt,                          // null or [64]
    char* smem,
    const ull* __restrict__ thoughtTag,   // null or encoder hTag buf0 (thought w/ tag 64)
    const float* __restrict__ decWih,     // f32 [1536][1024] (only if thoughtTag)
    const float* __restrict__ dec_bih) {  // f32 [1536]       (only if thoughtTag)
  float* sH = (float*)smem;                 // 2048 f32 (8KB)
  float* sRed = (float*)(smem + 8192);      // 512*13 f32 (26.6KB)
  const int tid = threadIdx.x;
  const int i0 = slice << 5;
  const int il = tid & 31, kc = tid >> 5;   // 32 i x 16 k-chunks(32k each)
  const int kb0 = kc << 5;

  // ---- step-invariant weights -> 96 VGPRs ----
  float wrF[32], wzF[32], wnF[32];
  {
    const uint2* wp = whhB + i0 + il;
    #pragma unroll
    for (int k4 = 0; k4 < 8; ++k4) {
      #pragma unroll
      for (int j = 0; j < 4; ++j) {
        const int idx = (k4 << 2) + j;
        uint2 wv = wp[(size_t)(kb0 + idx) << 9];
        wrF[idx] = __uint_as_float(wv.x << 16);
        wzF[idx] = __uint_as_float(wv.x & 0xffff0000u);
        wnF[idx] = __uint_as_float(wv.y << 16);
      }
    }
  }

  // ---- tail invariants: bhh, tp (thought projection) ----
  float bh_r = 0.f, bh_z = 0.f, bh_n = 0.f;
  float tpr = 0.f, tpz = 0.f, tpn = 0.f;
  int gi = 0, bb = 0;
  if (tid < 128) {
    const int b = tid >> 5, i2 = tid & 31;
    gi = i0 + i2;
    bb = (bg << 2) + b;
    bh_r = bhh[gi]; bh_z = bhh[512 + gi]; bh_n = bhh[1024 + gi];
  }
  if (thoughtTag) {
    #pragma unroll
    for (int j = 0; j < 4; ++j) {
      ull v = __hip_atomic_load(thoughtTag + ((size_t)bg << 11) + (j << 9) + tid,
                                __ATOMIC_RELAXED, __HIP_MEMORY_SCOPE_AGENT);
      sH[(j << 9) + tid] = fmaxf(__uint_as_float((unsigned)v), 0.f);
    }
    __syncthreads();
    if (tid < 384) {
      const int b = tid / 96, j = tid % 96;
      const int g = j >> 5, i2 = j & 31;
      const int row = g * 512 + i0 + i2;
      const float4* w4 = (const float4*)(decWih + (size_t)row * 1024 + 512);
      const float* th = &sH[b << 9];
      float s = dec_bih[row];
      #pragma unroll 4
      for (int k = 0; k < 128; ++k) {
        float4 w = w4[k];
        float4 t4 = *(const float4*)&th[k << 2];
        s += w.x * t4.x + w.y * t4.y + w.z * t4.z + w.w * t4.w;
      }
      sRed[tid] = s;
    }
    __syncthreads();
    if (tid < 128) {
      const int b = tid >> 5, i2 = tid & 31;
      tpr = sRed[b * 96 + i2];
      tpz = sRed[b * 96 + 32 + i2];
      tpn = sRed[b * 96 + 64 + i2];
    }
    __syncthreads();
  }

  #pragma unroll 1
  for (int t = 0; t < Tt; ++t) {
    // poll + load h(t) (tag word = {step<<32 | f32}, buffer = t parity)
    {
      const ull* hb = hTag + ((size_t)(t & 1) << 14) + ((size_t)bg << 11);
      #pragma unroll
      for (int j = 0; j < 4; ++j) {
        const ull* p = hb + (j << 9) + tid;
        ull v = __hip_atomic_load(p, __ATOMIC_RELAXED, __HIP_MEMORY_SCOPE_AGENT);
        while ((unsigned)(v >> 32) != (unsigned)t) {
          __builtin_amdgcn_s_sleep(1);
          v = __hip_atomic_load(p, __ATOMIC_RELAXED, __HIP_MEMORY_SCOPE_AGENT);
        }
        sH[(j << 9) + tid] = __uint_as_float((unsigned)v);
      }
    }
    __syncthreads();   // B0

    float a[12];
    #pragma unroll
    for (int v = 0; v < 12; ++v) a[v] = 0.f;
    #pragma unroll
    for (int k4 = 0; k4 < 8; ++k4) {
      const int kb = kb0 + (k4 << 2);
      float4 hv0 = *(const float4*)&sH[kb];
      float4 hv1 = *(const float4*)&sH[512 + kb];
      float4 hv2 = *(const float4*)&sH[1024 + kb];
      float4 hv3 = *(const float4*)&sH[1536 + kb];
      const float* h0p = (const float*)&hv0;
      const float* h1p = (const float*)&hv1;
      const float* h2p = (const float*)&hv2;
      const float* h3p = (const float*)&hv3;
      #pragma unroll
      for (int j = 0; j < 4; ++j) {
        const int idx = (k4 << 2) + j;
        const float wr = wrF[idx], wz = wzF[idx], wn = wnF[idx];
        a[0]  = fmaf(wr, h0p[j], a[0]);  a[1]  = fmaf(wz, h0p[j], a[1]);  a[2]  = fmaf(wn, h0p[j], a[2]);
        a[3]  = fmaf(wr, h1p[j], a[3]);  a[4]  = fmaf(wz, h1p[j], a[4]);  a[5]  = fmaf(wn, h1p[j], a[5]);
        a[6]  = fmaf(wr, h2p[j], a[6]);  a[7]  = fmaf(wz, h2p[j], a[7]);  a[8]  = fmaf(wn, h2p[j], a[8]);
        a[9]  = fmaf(wr, h3p[j], a[9]);  a[10] = fmaf(wz, h3p[j], a[10]); a[11] = fmaf(wn, h3p[j], a[11]);
      }
    }
    {
      float* red = &sRed[tid * 13];
      #pragma unroll
      for (int v = 0; v < 12; ++v) red[v] = a[v];
    }
    __syncthreads();   // B1

    if (tid < 128) {
      const int b = tid >> 5, i2 = tid & 31;
      float s0 = 0.f, s1 = 0.f, s2 = 0.f;
      #pragma unroll
      for (int kc2 = 0; kc2 < 16; ++kc2) {
        const float* rp = &sRed[(kc2 * 32 + i2) * 13 + b * 3];
        s0 += rp[0]; s1 += rp[1]; s2 += rp[2];
      }
      const float hr = s0 + bh_r;
      const float hz = s1 + bh_z;
      const float hn = s2 + bh_n;
      const size_t m = (size_t)bb * Tt + t;
      const float xr = xp[m * G3 + gi] + tpr;
      const float xz = xp[m * G3 + 512 + gi] + tpz;
      const float xn = xp[m * G3 + 1024 + gi] + tpn;
      const float rg = 1.f / (1.f + __expf(-(xr + hr)));
      const float zg = 1.f / (1.f + __expf(-(xz + hz)));
      const float ng = tanhf(xn + rg * hn);
      const float hnew = (1.f - zg) * ng + zg * sH[(b << 9) + gi];
      ull* dst = hTag + ((size_t)((t + 1) & 1) << 14) + ((size_t)bb << 9) + gi;
      __hip_atomic_store(dst, ((ull)(unsigned)(t + 1) << 32) | (ull)__float_as_uint(hnew),
                         __ATOMIC_RELAXED, __HIP_MEMORY_SCOPE_AGENT);
      if (decOutU) {
        // [t][b] layout, UC paired-u32 store: row r2=t*32+bb, col gi; even lane packs (gi, gi+1)
        unsigned bbits = bf16bits(hnew);
        unsigned pbits = __shfl_down(bbits, 1);
        if (!(tid & 1)) {
          const int r2 = (t << 5) + bb;
          __hip_atomic_store(decOutU + (((r2 << 9) + gi) >> 1), (pbits << 16) | bbits,
                             __ATOMIC_RELAXED, __HIP_MEMORY_SCOPE_AGENT);
        }
      }
    }
    __syncthreads();   // B2: drains UC stores (vmcnt 0) before flag
    if (doneCnt && tid == 0) {
      __hip_atomic_fetch_add(doneCnt + t, 1u, __ATOMIC_RELAXED, __HIP_MEMORY_SCOPE_AGENT);
    }
  }
}

// ---------------- 128x128 tile GEMM core (cached A+B, f32 out) for enc_fused dec_xp ----------------
__device__ __forceinline__ void gemm_tile_core(
    const int tid, const int m0, const int n0,
    const __hip_bfloat16* __restrict__ A, const __hip_bfloat16* __restrict__ B,
    float* __restrict__ C, int lda, int ldb, int ldc, int K, char* smem) {
  auto sA = (__hip_bfloat16(*)[64])smem;
  auto sB = (__hip_bfloat16(*)[64])(smem + 16384);
  const int l = tid & 63, w = tid >> 6;
  const int wm = (w & 1) << 6, wn = (w >> 1) << 6;
  const int lr = l & 15;
  const int lk = (l >> 4) << 3;
  const int lrow = (w << 3) + (l >> 3);
  const int lcol = (l & 7) << 3;

  f32x4 acc[4][4];
  #pragma unroll
  for (int i = 0; i < 4; ++i)
    #pragma unroll
    for (int j = 0; j < 4; ++j) acc[i][j] = {0.f, 0.f, 0.f, 0.f};

  for (int k0 = 0; k0 < K; k0 += 64) {
    #pragma unroll
    for (int rr = 0; rr < 4; ++rr) {
      gl_lds16(A + (size_t)(m0 + (rr << 5) + lrow) * lda + k0 + lcol, &sA[(rr << 5) + (w << 3)][0]);
      gl_lds16(B + (size_t)(n0 + (rr << 5) + lrow) * ldb + k0 + lcol, &sB[(rr << 5) + (w << 3)][0]);
    }
    __syncthreads();
    #pragma unroll
    for (int kk = 0; kk < 64; kk += 32) {
      short8 aF[4], bF[4];
      #pragma unroll
      for (int ms = 0; ms < 4; ++ms) aF[ms] = *(const short8*)(&sA[wm + (ms << 4) + lr][kk + lk]);
      #pragma unroll
      for (int ns = 0; ns < 4; ++ns) bF[ns] = *(const short8*)(&sB[wn + (ns << 4) + lr][kk + lk]);
      #pragma unroll
      for (int ms = 0; ms < 4; ++ms)
        #pragma unroll
        for (int ns = 0; ns < 4; ++ns)
          acc[ms][ns] = __builtin_amdgcn_mfma_f32_16x16x32_bf16(aF[ms], bF[ns], acc[ms][ns], 0, 0, 0);
    }
    __syncthreads();
  }

  float* sg = (float*)smem + w * 1088;
  const int r2w = l >> 4;
  const int cw = l & 15;
  const int rbase = r2w << 2;
  #pragma unroll
  for (int ms = 0; ms < 4; ++ms) {
    #pragma unroll
    for (int ns = 0; ns < 4; ++ns)
      #pragma unroll
      for (int r = 0; r < 4; ++r) sg[(rbase + r) * 68 + (ns << 4) + lr] = acc[ms][ns][r];
    #pragma unroll
    for (int qq = 0; qq < 4; ++qq) {
      const int srow2 = (qq << 2) + r2w;
      float4 v = *(const float4*)&sg[srow2 * 68 + (cw << 2)];
      *(float4*)&C[(size_t)(m0 + wm + (ms << 4) + srow2) * ldc + n0 + wn + (cw << 2)] = v;
    }
  }
}

// ---------------- logits tile core: A via CACHED global_load_lds ----------------
// Coherence: decOutU lines are write-once (UC, to LLC) and first READ strictly after the
// doneCnt gate -> cached read cannot observe a pre-write copy (validated round 15).
// Output rows remapped r2->m=(bb<<6)+t in epilogue; emits partials + bf16/f32 logits.
__device__ __forceinline__ void gemm_logits_core(
    const int tid, const int m0, const int n0,
    const __hip_bfloat16* __restrict__ Abf,  // decOut bf16, [t][b] rows, lda=512
    const __hip_bfloat16* __restrict__ B,    // outW_bf [32000][512]
    const float* __restrict__ out_b,
    float* __restrict__ outF, __hip_bfloat16* __restrict__ outBf,
    float2* __restrict__ partials, const int bfOut, char* smem) {
  auto sA = (__hip_bfloat16(*)[64])smem;
  auto sB = (__hip_bfloat16(*)[64])(smem + 16384);
  const int l = tid & 63, w = tid >> 6;
  const int wm = (w & 1) << 6, wn = (w >> 1) << 6;
  const int lr = l & 15;
  const int lk = (l >> 4) << 3;
  const int lrow = (w << 3) + (l >> 3);
  const int lcol = (l & 7) << 3;

  f32x4 acc[4][4];
  #pragma unroll
  for (int i = 0; i < 4; ++i)
    #pragma unroll
    for (int j = 0; j < 4; ++j) acc[i][j] = {0.f, 0.f, 0.f, 0.f};

  for (int k0 = 0; k0 < 512; k0 += 64) {
    #pragma unroll
    for (int rr = 0; rr < 4; ++rr) {
      gl_lds16(Abf + (size_t)(m0 + (rr << 5) + lrow) * 512 + k0 + lcol, &sA[(rr << 5) + (w << 3)][0]);
      gl_lds16(B + (size_t)(n0 + (rr << 5) + lrow) * 512 + k0 + lcol, &sB[(rr << 5) + (w << 3)][0]);
    }
    __syncthreads();
    #pragma unroll
    for (int kk = 0; kk < 64; kk += 32) {
      short8 aF[4], bF[4];
      #pragma unroll
      for (int ms = 0; ms < 4; ++ms) aF[ms] = *(const short8*)(&sA[wm + (ms << 4) + lr][kk + lk]);
      #pragma unroll
      for (int ns = 0; ns < 4; ++ns) bF[ns] = *(const short8*)(&sB[wn + (ns << 4) + lr][kk + lk]);
      #pragma unroll
      for (int ms = 0; ms < 4; ++ms)
        #pragma unroll
        for (int ns = 0; ns < 4; ++ns)
          acc[ms][ns] = __builtin_amdgcn_mfma_f32_16x16x32_bf16(aF[ms], bF[ns], acc[ms][ns], 0, 0, 0);
    }
    __syncthreads();
  }

  float* sg = (float*)smem + w * 1088;
  const int r2w = l >> 4;
  const int cw = l & 15;
  const int rbase = r2w << 2;
  #pragma unroll
  for (int ms = 0; ms < 4; ++ms) {
    #pragma unroll
    for (int ns = 0; ns < 4; ++ns)
      #pragma unroll
      for (int r = 0; r < 4; ++r) sg[(rbase + r) * 68 + (ns << 4) + lr] = acc[ms][ns][r];
    #pragma unroll
    for (int qq = 0; qq < 4; ++qq) {
      const int srow2 = (qq << 2) + r2w;
      float4 v = *(const float4*)&sg[srow2 * 68 + (cw << 2)];
      const int r2a = m0 + wm + (ms << 4) + srow2;          // [t][b] row
      const int mrow = ((r2a & 31) << 6) + (r2a >> 5);      // final row b*64+t
      const int col = n0 + wn + (cw << 2);
      float4 b1 = *(const float4*)&out_b[col];
      v.x += b1.x; v.y += b1.y; v.z += b1.z; v.w += b1.w;
      float m4 = fmaxf(fmaxf(v.x, v.y), fmaxf(v.z, v.w));
      #pragma unroll
      for (int hop = 1; hop < 16; hop <<= 1) m4 = fmaxf(m4, __shfl_xor(m4, hop));
      float e = __expf(v.x - m4) + __expf(v.y - m4) + __expf(v.z - m4) + __expf(v.w - m4);
      #pragma unroll
      for (int hop = 1; hop < 16; hop <<= 1) e += __shfl_xor(e, hop);
      if (cw == 0) partials[(size_t)mrow * 500 + ((n0 >> 6) + (wn >> 6))] = make_float2(m4, e);
      if (bfOut) {
        union { __hip_bfloat16 h[4]; uint2 u; } o;
        o.h[0] = __float2bfloat16(v.x);
        o.h[1] = __float2bfloat16(v.y);
        o.h[2] = __float2bfloat16(v.z);
        o.h[3] = __float2bfloat16(v.w);
        *(uint2*)&outBf[(size_t)mrow * Vv + col] = o.u;
      } else {
        *(float4*)&outF[(size_t)mrow * Vv + col] = v;
      }
    }
  }
}

// ---------------- work-stealing logits worker loop (round-17) ----------------
// ALL blocks (GEMM workers immediately; GRU blocks after finishing their 64 steps)
// pull tile-pairs from an atomic queue in ascending-mT order; each pair gated on
// doneCnt[4*mT+3]==128. Waits are acyclic (only on GRU progress). Output is
// schedule-independent (each tile computed once).
__device__ __forceinline__ void logits_worker_loop(
    unsigned* __restrict__ workCtr, unsigned* __restrict__ doneCnt,
    const __hip_bfloat16* __restrict__ decOut,
    const __hip_bfloat16* __restrict__ outW_bf, const float* __restrict__ out_b,
    float* __restrict__ outF, __hip_bfloat16* __restrict__ logitsBf,
    float2* __restrict__ partials, const int bfOut, char* smem, int* sPair) {
  const int tid = threadIdx.x;
  for (;;) {
    if (tid == 0) {
      *sPair = (int)__hip_atomic_fetch_add(workCtr, 1u, __ATOMIC_RELAXED, __HIP_MEMORY_SCOPE_AGENT);
    }
    __syncthreads();
    const int p = *sPair;
    if (p >= 2000) break;                // 4000 tiles = 2000 pairs
    const int mT = (2 * p + 1) / 250;    // max mTile of the pair (tiles m-major)
    const int thi = 4 * mT + 3;          // last timestep these rows need
    if (tid == 0) {
      while (__hip_atomic_load(doneCnt + thi, __ATOMIC_RELAXED, __HIP_MEMORY_SCOPE_AGENT) < 128u)
        __builtin_amdgcn_s_sleep(4);
    }
    __syncthreads();
    const int half = tid >> 8;
    const int tile = 2 * p + half;
    gemm_logits_core(tid & 255, (tile / 250) << 7, (tile % 250) << 7,
                     decOut, outW_bf, out_b, outF, logitsBf,
                     partials, bfOut, smem + (half << 15));
    __syncthreads();   // protect smem + sPair against next iteration
  }
}

// ---------------- FUSED: encoder GRU (XCDs 0-3) || dec_xp GEMM + outW cvt (XCDs 4-7) ----------------
__global__ __launch_bounds__(512, 1) void enc_fused_k(
    const float* __restrict__ enc_xp, const uint2* __restrict__ whhB_e,
    const float* __restrict__ enc_bhh, ull* __restrict__ hTag_e,
    const __hip_bfloat16* __restrict__ decX_bf, const __hip_bfloat16* __restrict__ decWih_bf,
    float* __restrict__ dec_xp,
    const float* __restrict__ out_W, __hip_bfloat16* __restrict__ outW_bf) {
  __shared__ __align__(16) char smem[65536];
  const int blk = blockIdx.x;
  const int xcd = blk & 7;
  if (xcd < 4) {
    const int g = ((blk >> 3) << 2) + xcd;              // 0..127
    gru_core(g & 15, g >> 4, enc_xp, whhB_e, enc_bhh, hTag_e, nullptr, nullptr, smem,
             nullptr, nullptr, nullptr);
  } else {
    const int wkr = ((blk >> 3) << 2) + (xcd - 4);      // 0..127
    if (wkr < 96) {
      const int half = threadIdx.x >> 8;
      const int tile = (wkr << 1) + half;               // 0..191
      const int m0 = (tile & 15) << 7;
      const int n0 = (tile >> 4) << 7;
      gemm_tile_core(threadIdx.x & 255, m0, n0, decX_bf, decWih_bf, dec_xp,
                     512, 1024, G3, 512, smem + (half << 15));
    } else {
      const int n4 = Vv * Hh / 4;
      for (int i = ((wkr - 96) << 9) + threadIdx.x; i < n4; i += 32 * 512) {
        float4 v = ((const float4*)out_W)[i];
        union { __hip_bfloat16 h[4]; uint2 u; } o;
        o.h[0] = __float2bfloat16(v.x);
        o.h[1] = __float2bfloat16(v.y);
        o.h[2] = __float2bfloat16(v.z);
        o.h[3] = __float2bfloat16(v.w);
        ((uint2*)outW_bf)[i] = o.u;
      }
    }
  }
}

// ---------------- FUSED: decoder GRU (XCDs 0-3) || logits workers (XCDs 4-7 + retired GRU blocks) ----------------
__global__ __launch_bounds__(512, 1) void dec_fused_k(
    const float* __restrict__ dec_xp, const uint2* __restrict__ whhB_d,
    const float* __restrict__ dec_bhh,
    const ull* __restrict__ thoughtTag, const float* __restrict__ dec_Wih,
    const float* __restrict__ dec_bih,
    ull* __restrict__ hTag_d, unsigned* __restrict__ decOutU, unsigned* __restrict__ doneCnt,
    unsigned* __restrict__ workCtr,
    const __hip_bfloat16* __restrict__ outW_bf, const float* __restrict__ out_b,
    float* __restrict__ outF, __hip_bfloat16* __restrict__ logitsBf,
    float2* __restrict__ partials, int bfOut) {
  __shared__ __align__(16) char smem[65536];
  __shared__ int sPair;
  const int blk = blockIdx.x;
  const int xcd = blk & 7;
  if (xcd < 4) {
    const int g = ((blk >> 3) << 2) + xcd;              // 0..127
    gru_core(g & 15, g >> 4, dec_xp, whhB_d, dec_bhh, hTag_d, decOutU, doneCnt, smem,
             thoughtTag, dec_Wih, dec_bih);
    // fall through: retired GRU block joins the tile pool (doneCnt[63] already set)
  }
  logits_worker_loop(workCtr, doneCnt, (const __hip_bfloat16*)decOutU,
                     outW_bf, out_b, outF, logitsBf, partials, bfOut, smem, &sPair);
}

// ---------------- final log-softmax (f32 logits in place) ----------------
__global__ __launch_bounds__(256) void lsm_final_k(float* __restrict__ X,
                                                   const float2* __restrict__ P) {
  const int row = blockIdx.x;
  const int tid = threadIdx.x;
  float m = -3.4e38f, s = 0.f;
  for (int j = tid; j < 500; j += 256) {
    float2 p = P[(size_t)row * 500 + j];
    if (p.x > m) { s = s * __expf(m - p.x) + p.y; m = p.x; }
    else         { s += p.y * __expf(p.x - m); }
  }
  #pragma unroll
  for (int off2 = 32; off2 > 0; off2 >>= 1) {
    float mo = __shfl_down(m, off2);
    float so = __shfl_down(s, off2);
    float M = fmaxf(m, mo);
    s = s * __expf(m - M) + so * __expf(mo - M);
    m = M;
  }
  __shared__ float sm[4], ss[4];
  if ((tid & 63) == 0) { sm[tid >> 6] = m; ss[tid >> 6] = s; }
  __syncthreads();
  const float M4 = fmaxf(fmaxf(sm[0], sm[1]), fmaxf(sm[2], sm[3]));
  const float S = ss[0] * __expf(sm[0] - M4) + ss[1] * __expf(sm[1] - M4) +
                  ss[2] * __expf(sm[2] - M4) + ss[3] * __expf(sm[3] - M4);
  const float c = M4 + __logf(S);
  float4* p4 = (float4*)(X + (size_t)row * Vv);
  for (int j = tid; j < Vv / 4; j += 256) {
    float4 v = p4[j];
    v.x -= c; v.y -= c; v.z -= c; v.w -= c;
    p4[j] = v;
  }
}

// ---------------- final log-softmax (bf16 logits -> f32 d_out) ----------------
__global__ __launch_bounds__(256) void lsm_final2_k(float* __restrict__ X,
                                                    const __hip_bfloat16* __restrict__ L,
                                                    const float2* __restrict__ P) {
  const int row = blockIdx.x;
  const int tid = threadIdx.x;
  float m = -3.4e38f, s = 0.f;
  for (int j = tid; j < 500; j += 256) {
    float2 p = P[(size_t)row * 500 + j];
    if (p.x > m) { s = s * __expf(m - p.x) + p.y; m = p.x; }
    else         { s += p.y * __expf(p.x - m); }
  }
  #pragma unroll
  for (int off2 = 32; off2 > 0; off2 >>= 1) {
    float mo = __shfl_down(m, off2);
    float so = __shfl_down(s, off2);
    float M = fmaxf(m, mo);
    s = s * __expf(m - M) + so * __expf(mo - M);
    m = M;
  }
  __shared__ float sm[4], ss[4];
  if ((tid & 63) == 0) { sm[tid >> 6] = m; ss[tid >> 6] = s; }
  __syncthreads();
  const float M4 = fmaxf(fmaxf(sm[0], sm[1]), fmaxf(sm[2], sm[3]));
  const float S = ss[0] * __expf(sm[0] - M4) + ss[1] * __expf(sm[1] - M4) +
                  ss[2] * __expf(sm[2] - M4) + ss[3] * __expf(sm[3] - M4);
  const float c = M4 + __logf(S);
  const short8* p8 = (const short8*)(L + (size_t)row * Vv);
  float4* o4 = (float4*)(X + (size_t)row * Vv);
  for (int j = tid; j < Vv / 8; j += 256) {
    short8 sv = p8[j];
    float4 a, b;
    a.x = __uint_as_float(((unsigned)(unsigned short)sv[0]) << 16) - c;
    a.y = __uint_as_float(((unsigned)(unsigned short)sv[1]) << 16) - c;
    a.z = __uint_as_float(((unsigned)(unsigned short)sv[2]) << 16) - c;
    a.w = __uint_as_float(((unsigned)(unsigned short)sv[3]) << 16) - c;
    b.x = __uint_as_float(((unsigned)(unsigned short)sv[4]) << 16) - c;
    b.y = __uint_as_float(((unsigned)(unsigned short)sv[5]) << 16) - c;
    b.z = __uint_as_float(((unsigned)(unsigned short)sv[6]) << 16) - c;
    b.w = __uint_as_float(((unsigned)(unsigned short)sv[7]) << 16) - c;
    o4[(j << 1)] = a;
    o4[(j << 1) + 1] = b;
  }
}

}  // namespace

extern "C" void kernel_launch(void* const* d_in, const int* in_sizes, int n_in,
                              void* d_out, int out_size, void* d_ws, size_t ws_size,
                              hipStream_t stream) {
  (void)in_sizes; (void)n_in; (void)out_size;
  const int*   in_seq  = (const int*)d_in[0];
  const int*   tgt_seq = (const int*)d_in[1];
  const float* enc_emb = (const float*)d_in[2];
  const float* enc_Wih = (const float*)d_in[3];
  const float* enc_Whh = (const float*)d_in[4];
  const float* enc_bih = (const float*)d_in[5];
  const float* enc_bhh = (const float*)d_in[6];
  const float* dec_emb = (const float*)d_in[7];
  const float* dec_Wih = (const float*)d_in[8];
  const float* dec_Whh = (const float*)d_in[9];
  const float* dec_bih = (const float*)d_in[10];
  const float* dec_bhh = (const float*)d_in[11];
  const float* out_W   = (const float*)d_in[12];
  const float* out_b   = (const float*)d_in[13];
  float* out = (float*)d_out;

  char* ws = (char*)d_ws;
  size_t off = 0;
  auto alloc = [&](size_t bytes) -> void* {
    void* p = (void*)(ws + off);
    off += (bytes + 255) & ~(size_t)255;
    return p;
  };
  uint2* whhB_e            = (uint2*)alloc((size_t)512 * 512 * 8);
  uint2* whhB_d            = (uint2*)alloc((size_t)512 * 512 * 8);
  __hip_bfloat16* encWih_bf = (__hip_bfloat16*)alloc((size_t)1536 * 512 * 2);
  __hip_bfloat16* decWih_bf = (__hip_bfloat16*)alloc((size_t)1536 * 1024 * 2);
  __hip_bfloat16* outW_bf   = (__hip_bfloat16*)alloc((size_t)32000 * 512 * 2);
  __hip_bfloat16* encX_bf   = (__hip_bfloat16*)alloc((size_t)2048 * 512 * 2);
  __hip_bfloat16* decX_bf   = (__hip_bfloat16*)alloc((size_t)2048 * 512 * 2);
  float* enc_xp            = (float*)alloc((size_t)2048 * 1536 * 4);
  float* dec_xp            = (float*)alloc((size_t)2048 * 1536 * 4);
  ull* hTag_e              = (ull*)alloc((size_t)2 * 32 * 512 * 8);   // 256KB
  ull* hTag_d              = (ull*)alloc((size_t)2 * 32 * 512 * 8);   // 256KB (contiguous)
  unsigned* doneCnt        = (unsigned*)alloc((size_t)64 * 4);        // 256B (contiguous)
  unsigned* workCtr        = (unsigned*)alloc((size_t)64 * 4);        // 256B (contiguous)
  unsigned* decOutU        = (unsigned*)alloc((size_t)2048 * 512 * 2);// 2MB packed bf16 [t][b]
  float2* partials         = (float2*)alloc((size_t)2048 * 500 * 8);  // 8.2MB
  __hip_bfloat16* logitsBf  = (__hip_bfloat16*)alloc((size_t)2048 * Vv * 2);  // 131MB (optional)
  const bool bfLogits = (off <= ws_size);

  // --- merged preprocessing: cvt x2 | pack x2 | zero hTag_e+hTag_d+doneCnt+workCtr ---
  prep_k<<<2689, 256, 0, stream>>>(enc_Wih, encWih_bf, dec_Wih, decWih_bf,
                                   enc_Whh, whhB_e, dec_Whh, whhB_d, (uint4*)hTag_e);

  // --- embeddings ---
  embed_k<<<2048, 128, 0, stream>>>(in_seq, enc_emb, encX_bf, 0);
  embed_k<<<2048, 128, 0, stream>>>(tgt_seq, dec_emb, decX_bf, 1);

  // --- encoder xp = enc_x @ Wih^T + bih : [2048,1536] ---
  gemm_bf16_k<<<192, 256, 0, stream>>>(encX_bf, encWih_bf, enc_xp,
                                       512, 512, G3, 512, enc_bih, 16);

  // --- FUSED: encoder GRU (XCDs 0-3) || dec_xp GEMM + outW cvt (XCDs 4-7) ---
  enc_fused_k<<<256, 512, 0, stream>>>(enc_xp, whhB_e, enc_bhh, hTag_e,
                                       decX_bf, decWih_bf, dec_xp, out_W, outW_bf);
  // thought = h(64) w/ tag 64 lives in hTag_e buffer 0

  // --- FUSED: decoder GRU (XCDs 0-3) || logits workers (XCDs 4-7; GRU blocks join after t=63) ---
  dec_fused_k<<<256, 512, 0, stream>>>(dec_xp, whhB_d, dec_bhh,
                                       hTag_e, dec_Wih, dec_bih,
                                       hTag_d, decOutU, doneCnt, workCtr,
                                       outW_bf, out_b,
                                       out, logitsBf, partials, bfLogits ? 1 : 0);

  // --- final log-softmax ---
  if (bfLogits) {
    lsm_final2_k<<<2048, 256, 0, stream>>>(out, logitsBf, partials);
  } else {
    lsm_final_k<<<2048, 256, 0, stream>>>(out, partials);
  }
}